// Round 1
// baseline (2172.828 us; speedup 1.0000x reference)
//
#include <hip/hip_runtime.h>

#define D 128

// ---------------------------------------------------------------------------
// scatter: for each incidence i:
//   acc[dst_idx[i]][:] += (w_num[src_idx[i]] / w_den[dst_idx[i]]) * feat[src_idx[i]][:]
// 32 threads per incidence, 4 floats (one float4 gather) per thread.
// ---------------------------------------------------------------------------
__global__ void __launch_bounds__(256) scatter_kernel(
    const float* __restrict__ feat,   // [n_src, D]
    const float* __restrict__ w_num,  // [n_src] numerator, indexed by src
    const float* __restrict__ w_den,  // [n_dst] denominator, indexed by dst
    const int*   __restrict__ src_idx,
    const int*   __restrict__ dst_idx,
    float*       __restrict__ acc,    // [n_dst, D], pre-zeroed
    int n_inc)
{
    int gid = blockIdx.x * 256 + threadIdx.x;
    int inc = gid >> 5;
    if (inc >= n_inc) return;
    int c = (gid & 31) << 2;

    int s = src_idx[inc];
    int t = dst_idx[inc];
    float w = w_num[s] / w_den[t];

    float4 v = *reinterpret_cast<const float4*>(feat + (size_t)s * D + c);
    float* dst = acc + (size_t)t * D + c;
    atomicAdd(dst + 0, w * v.x);
    atomicAdd(dst + 1, w * v.y);
    atomicAdd(dst + 2, w * v.z);
    atomicAdd(dst + 3, w * v.w);
}

// ---------------------------------------------------------------------------
// row-wise GEMM: out_row = f(in_row @ W^T + bias) for D=128.
// MODE 0: out  = in@W^T + b
// MODE 1: out += relu(in@W^T + b)
// MODE 2: out  = relu(in@W^T + b)   (in may alias out: tile staged in LDS first)
// Block: 256 threads, 64 rows. Thread (tx = tid&15, gr = tid>>4) computes
// rows 4*gr..4*gr+3  x  cols {tx + 16*j, j=0..7}  (strided cols -> LDS-conflict-free B reads)
// ---------------------------------------------------------------------------
template <int MODE>
__global__ void __launch_bounds__(256) rowgemm_kernel(
    const float* __restrict__ in,    // [nrows, D]
    const float* __restrict__ W,     // [D, D] row-major; out[j] uses W[j][k]
    const float* __restrict__ bias,  // [D]
    float*       __restrict__ out,   // [nrows, D]
    int nrows)
{
    __shared__ float A[64][D + 4];   // padded: row-stride 132 -> 2-way max on reads
    __shared__ float Bt[32][D + 4];  // Bt[kk][j] = W[j][k0+kk]

    const int tid = threadIdx.x;
    const int r0  = blockIdx.x * 64;
    const int tx  = tid & 15;
    const int gr  = tid >> 4;        // 0..15, 4 rows each

    // ---- stage A tile (64 x 128), zero-fill out-of-range rows ----
    #pragma unroll
    for (int it = 0; it < 8; ++it) {
        int e   = tid + it * 256;       // float4 id in [0, 2048)
        int row = e >> 5;
        int c4  = (e & 31) << 2;
        int grow = r0 + row;
        float4 v = make_float4(0.f, 0.f, 0.f, 0.f);
        if (grow < nrows)
            v = *reinterpret_cast<const float4*>(in + (size_t)grow * D + c4);
        *reinterpret_cast<float4*>(&A[row][c4]) = v;
    }

    float acc[4][8];
    #pragma unroll
    for (int i = 0; i < 4; ++i)
        #pragma unroll
        for (int j = 0; j < 8; ++j) acc[i][j] = 0.f;

    for (int kt = 0; kt < 4; ++kt) {
        __syncthreads();   // A ready (kt=0) / previous Bt reads done
        // ---- stage Bt[kk][j] = W[j][kt*32+kk]  (32 x 128) ----
        #pragma unroll
        for (int it = 0; it < 4; ++it) {
            int e  = tid + it * 256;    // float4 id in [0, 1024)
            int j  = e >> 3;
            int kq = (e & 7) << 2;
            float4 w4 = *reinterpret_cast<const float4*>(W + (size_t)j * D + kt * 32 + kq);
            Bt[kq + 0][j] = w4.x;
            Bt[kq + 1][j] = w4.y;
            Bt[kq + 2][j] = w4.z;
            Bt[kq + 3][j] = w4.w;
        }
        __syncthreads();

        #pragma unroll 4
        for (int kk = 0; kk < 32; ++kk) {
            int k = kt * 32 + kk;
            float a[4], b[8];
            #pragma unroll
            for (int i = 0; i < 4; ++i) a[i] = A[4 * gr + i][k];
            #pragma unroll
            for (int j = 0; j < 8; ++j) b[j] = Bt[kk][tx + 16 * j];
            #pragma unroll
            for (int i = 0; i < 4; ++i)
                #pragma unroll
                for (int j = 0; j < 8; ++j)
                    acc[i][j] = fmaf(a[i], b[j], acc[i][j]);
        }
    }

    // ---- epilogue ----
    float bv[8];
    #pragma unroll
    for (int j = 0; j < 8; ++j) bv[j] = bias[tx + 16 * j];

    #pragma unroll
    for (int i = 0; i < 4; ++i) {
        int row = r0 + 4 * gr + i;
        if (row >= nrows) continue;
        #pragma unroll
        for (int j = 0; j < 8; ++j) {
            int col = tx + 16 * j;
            float x = acc[i][j] + bv[j];
            size_t o = (size_t)row * D + col;
            if (MODE == 0) out[o] = x;
            if (MODE == 1) out[o] += fmaxf(x, 0.f);
            if (MODE == 2) out[o] = fmaxf(x, 0.f);
        }
    }
}

// ---------------------------------------------------------------------------
extern "C" void kernel_launch(void* const* d_in, const int* in_sizes, int n_in,
                              void* d_out, int out_size, void* d_ws, size_t ws_size,
                              hipStream_t stream)
{
    const float* vfeat = (const float*)d_in[0];
    const float* efeat = (const float*)d_in[1];
    const float* vrw   = (const float*)d_in[2];   // v_reg_weight [V]
    const float* vrs   = (const float*)d_in[3];   // v_reg_sum    [V]
    const float* erw   = (const float*)d_in[4];   // e_reg_weight [E]
    const float* ers   = (const float*)d_in[5];   // e_reg_sum    [E]
    const float* W_ve  = (const float*)d_in[6];
    const float* b_ve  = (const float*)d_in[7];
    const float* W_ev  = (const float*)d_in[8];
    const float* b_ev  = (const float*)d_in[9];
    const float* W_ef  = (const float*)d_in[10];
    const float* b_ef  = (const float*)d_in[11];
    const int* node_idx = (const int*)d_in[12];
    const int* edge_idx = (const int*)d_in[13];

    const int V = in_sizes[0] / D;   // 100000
    const int E = in_sizes[1] / D;   // 40000
    const int I = in_sizes[12];      // 600000

    float* vfeat_out = (float*)d_out;                       // [V, D]
    float* efeat_out = (float*)d_out + (size_t)V * D;       // [E, D]
    // acc_e scratch lives in the (not-yet-needed) vfeat_out region: E*D <= V*D
    float* acc_e = vfeat_out;

    const int scatter_blocks = (I * 32 + 255) / 256;

    // 1. acc_e = 0
    hipMemsetAsync(acc_e, 0, (size_t)E * D * sizeof(float), stream);
    // 2. acc_e[e] += (v_reg_weight[n] / e_reg_sum[e]) * vfeat[n]  over incidences
    scatter_kernel<<<scatter_blocks, 256, 0, stream>>>(
        vfeat, vrw, ers, node_idx, edge_idx, acc_e, I);
    // 3. efeat_out = efeat @ W_ef^T + b_ef
    rowgemm_kernel<0><<<(E + 63) / 64, 256, 0, stream>>>(efeat, W_ef, b_ef, efeat_out, E);
    // 4. efeat_out += relu(acc_e @ W_ve^T + b_ve)
    rowgemm_kernel<1><<<(E + 63) / 64, 256, 0, stream>>>(acc_e, W_ve, b_ve, efeat_out, E);
    // 5. acc_v = 0 (reuse vfeat_out region; acc_e now dead)
    hipMemsetAsync(vfeat_out, 0, (size_t)V * D * sizeof(float), stream);
    // 6. acc_v[n] += (e_reg_weight[e] / v_reg_sum[n]) * efeat_out[e]  over incidences
    scatter_kernel<<<scatter_blocks, 256, 0, stream>>>(
        efeat_out, erw, vrs, edge_idx, node_idx, vfeat_out, I);
    // 7. vfeat_out = relu(acc_v @ W_ev^T + b_ev)   (in-place)
    rowgemm_kernel<2><<<(V + 63) / 64, 256, 0, stream>>>(vfeat_out, W_ev, b_ev, vfeat_out, V);
}

// Round 2
// 442.024 us; speedup vs baseline: 4.9156x; 4.9156x over previous
//
#include <hip/hip_runtime.h>

#define D 128
#define SCAN_CHUNK 4096   // elements per scan block (1024 threads x 4)

// ---------------------------------------------------------------------------
// Fallback atomic scatter (round-1 kernel) — used only if ws_size too small.
// ---------------------------------------------------------------------------
__global__ void __launch_bounds__(256) scatter_kernel(
    const float* __restrict__ feat, const float* __restrict__ w_num,
    const float* __restrict__ w_den, const int* __restrict__ src_idx,
    const int* __restrict__ dst_idx, float* __restrict__ acc, int n_inc)
{
    int gid = blockIdx.x * 256 + threadIdx.x;
    int inc = gid >> 5;
    if (inc >= n_inc) return;
    int c = (gid & 31) << 2;
    int s = src_idx[inc];
    int t = dst_idx[inc];
    float w = w_num[s] / w_den[t];
    float4 v = *reinterpret_cast<const float4*>(feat + (size_t)s * D + c);
    float* dst = acc + (size_t)t * D + c;
    atomicAdd(dst + 0, w * v.x);
    atomicAdd(dst + 1, w * v.y);
    atomicAdd(dst + 2, w * v.z);
    atomicAdd(dst + 3, w * v.w);
}

// ---------------------------------------------------------------------------
// CSR build: histogram both directions in one pass.
// ---------------------------------------------------------------------------
__global__ void __launch_bounds__(256) hist2_kernel(
    const int* __restrict__ node_idx, const int* __restrict__ edge_idx,
    int* __restrict__ cnt_e, int* __restrict__ cnt_v, int n)
{
    int i = blockIdx.x * 256 + threadIdx.x;
    if (i >= n) return;
    atomicAdd(&cnt_e[edge_idx[i]], 1);
    atomicAdd(&cnt_v[node_idx[i]], 1);
}

// Per-block exclusive scan (1024 thr x 4 elems); block total -> blocksums.
__global__ void __launch_bounds__(1024) scan_block_kernel(
    const int* __restrict__ in, int* __restrict__ out,
    int* __restrict__ blocksums, int n)
{
    __shared__ int lds[1024];
    const int tid = threadIdx.x;
    const int idx = blockIdx.x * SCAN_CHUNK + tid * 4;
    int4 v = make_int4(0, 0, 0, 0);
    if (idx + 3 < n) v = *reinterpret_cast<const int4*>(in + idx);
    else {
        if (idx + 0 < n) v.x = in[idx + 0];
        if (idx + 1 < n) v.y = in[idx + 1];
        if (idx + 2 < n) v.z = in[idx + 2];
        if (idx + 3 < n) v.w = in[idx + 3];
    }
    lds[tid] = v.x + v.y + v.z + v.w;
    __syncthreads();
    for (int off = 1; off < 1024; off <<= 1) {
        int t = lds[tid];
        int u = (tid >= off) ? lds[tid - off] : 0;
        __syncthreads();
        lds[tid] = t + u;
        __syncthreads();
    }
    int excl = tid ? lds[tid - 1] : 0;
    if (blocksums && tid == 1023) blocksums[blockIdx.x] = lds[1023];
    int4 o;
    o.x = excl;
    o.y = o.x + v.x;
    o.z = o.y + v.y;
    o.w = o.z + v.z;
    if (idx + 3 < n) *reinterpret_cast<int4*>(out + idx) = o;
    else {
        if (idx + 0 < n) out[idx + 0] = o.x;
        if (idx + 1 < n) out[idx + 1] = o.y;
        if (idx + 2 < n) out[idx + 2] = o.z;
        if (idx + 3 < n) out[idx + 3] = o.w;
    }
}

__global__ void __launch_bounds__(256) scan_add_kernel(
    int* __restrict__ out, const int* __restrict__ bsums, int n)
{
    int idx = (blockIdx.x * 256 + threadIdx.x) * 4;
    if (idx >= n) return;
    int add = bsums[idx / SCAN_CHUNK];
    if (idx + 3 < n) {
        int4 v = *reinterpret_cast<int4*>(out + idx);
        v.x += add; v.y += add; v.z += add; v.w += add;
        *reinterpret_cast<int4*>(out + idx) = v;
    } else {
        for (int k = 0; k < 4 && idx + k < n; ++k) out[idx + k] += add;
    }
}

// Scatter incidences into CSR order for both directions.
__global__ void __launch_bounds__(256) permute2_kernel(
    const int* __restrict__ node_idx, const int* __restrict__ edge_idx,
    int* __restrict__ cur_e, int* __restrict__ cur_v,
    int* __restrict__ sorted_n, int* __restrict__ sorted_e, int n)
{
    int i = blockIdx.x * 256 + threadIdx.x;
    if (i >= n) return;
    int nv = node_idx[i], ev = edge_idx[i];
    int pe = atomicAdd(&cur_e[ev], 1);
    sorted_n[pe] = nv;
    int pv = atomicAdd(&cur_v[nv], 1);
    sorted_e[pv] = ev;
}

// ---------------------------------------------------------------------------
// gather-sum: one wave (64 lanes) per destination row, float2 per lane.
// out[r][:] = ( sum_{i in seg(r)} w_num[src_i] * feat[src_i][:] ) / w_den[r]
// Writes EVERY row (zeros for empty segments) -> no pre-memset needed.
// ---------------------------------------------------------------------------
__global__ void __launch_bounds__(256) gather_kernel(
    const float* __restrict__ feat,       // [n_src, D]
    const float* __restrict__ w_num,      // [n_src]
    const float* __restrict__ w_den,      // [n_dst]
    const int*   __restrict__ sorted_src, // [I] grouped by dst
    const int*   __restrict__ off,        // [n_dst] segment starts
    const int*   __restrict__ cnt,        // [n_dst] segment lengths
    float*       __restrict__ out,        // [n_dst, D]
    int n_dst)
{
    int row = blockIdx.x * 4 + (threadIdx.x >> 6);
    if (row >= n_dst) return;
    int c = (threadIdx.x & 63) * 2;
    int start = off[row];
    int end = start + cnt[row];
    float inv = 1.0f / w_den[row];
    float sx = 0.f, sy = 0.f;
    for (int i = start; i < end; ++i) {
        int src = sorted_src[i];
        float w = w_num[src];
        float2 f = *reinterpret_cast<const float2*>(feat + (size_t)src * D + c);
        sx = fmaf(w, f.x, sx);
        sy = fmaf(w, f.y, sy);
    }
    *reinterpret_cast<float2*>(out + (size_t)row * D + c) = make_float2(sx * inv, sy * inv);
}

// ---------------------------------------------------------------------------
// row-wise GEMM (unchanged from round 1): out_row = f(in_row @ W^T + bias).
// MODE 0: out = x ; MODE 1: out += relu(x) ; MODE 2: out = relu(x) (in==out ok)
// ---------------------------------------------------------------------------
template <int MODE>
__global__ void __launch_bounds__(256) rowgemm_kernel(
    const float* __restrict__ in, const float* __restrict__ W,
    const float* __restrict__ bias, float* __restrict__ out, int nrows)
{
    __shared__ float A[64][D + 4];
    __shared__ float Bt[32][D + 4];

    const int tid = threadIdx.x;
    const int r0  = blockIdx.x * 64;
    const int tx  = tid & 15;
    const int gr  = tid >> 4;

    #pragma unroll
    for (int it = 0; it < 8; ++it) {
        int e = tid + it * 256;
        int row = e >> 5;
        int c4 = (e & 31) << 2;
        int grow = r0 + row;
        float4 v = make_float4(0.f, 0.f, 0.f, 0.f);
        if (grow < nrows)
            v = *reinterpret_cast<const float4*>(in + (size_t)grow * D + c4);
        *reinterpret_cast<float4*>(&A[row][c4]) = v;
    }

    float acc[4][8];
    #pragma unroll
    for (int i = 0; i < 4; ++i)
        #pragma unroll
        for (int j = 0; j < 8; ++j) acc[i][j] = 0.f;

    for (int kt = 0; kt < 4; ++kt) {
        __syncthreads();
        #pragma unroll
        for (int it = 0; it < 4; ++it) {
            int e = tid + it * 256;
            int j = e >> 3;
            int kq = (e & 7) << 2;
            float4 w4 = *reinterpret_cast<const float4*>(W + (size_t)j * D + kt * 32 + kq);
            Bt[kq + 0][j] = w4.x;
            Bt[kq + 1][j] = w4.y;
            Bt[kq + 2][j] = w4.z;
            Bt[kq + 3][j] = w4.w;
        }
        __syncthreads();

        #pragma unroll 4
        for (int kk = 0; kk < 32; ++kk) {
            int k = kt * 32 + kk;
            float a[4], b[8];
            #pragma unroll
            for (int i = 0; i < 4; ++i) a[i] = A[4 * gr + i][k];
            #pragma unroll
            for (int j = 0; j < 8; ++j) b[j] = Bt[kk][tx + 16 * j];
            #pragma unroll
            for (int i = 0; i < 4; ++i)
                #pragma unroll
                for (int j = 0; j < 8; ++j)
                    acc[i][j] = fmaf(a[i], b[j], acc[i][j]);
        }
    }

    float bv[8];
    #pragma unroll
    for (int j = 0; j < 8; ++j) bv[j] = bias[tx + 16 * j];

    #pragma unroll
    for (int i = 0; i < 4; ++i) {
        int row = r0 + 4 * gr + i;
        if (row >= nrows) continue;
        #pragma unroll
        for (int j = 0; j < 8; ++j) {
            int col = tx + 16 * j;
            float x = acc[i][j] + bv[j];
            size_t o = (size_t)row * D + col;
            if (MODE == 0) out[o] = x;
            if (MODE == 1) out[o] += fmaxf(x, 0.f);
            if (MODE == 2) out[o] = fmaxf(x, 0.f);
        }
    }
}

// ---------------------------------------------------------------------------
extern "C" void kernel_launch(void* const* d_in, const int* in_sizes, int n_in,
                              void* d_out, int out_size, void* d_ws, size_t ws_size,
                              hipStream_t stream)
{
    const float* vfeat = (const float*)d_in[0];
    const float* efeat = (const float*)d_in[1];
    const float* vrw   = (const float*)d_in[2];
    const float* vrs   = (const float*)d_in[3];
    const float* erw   = (const float*)d_in[4];
    const float* ers   = (const float*)d_in[5];
    const float* W_ve  = (const float*)d_in[6];
    const float* b_ve  = (const float*)d_in[7];
    const float* W_ev  = (const float*)d_in[8];
    const float* b_ev  = (const float*)d_in[9];
    const float* W_ef  = (const float*)d_in[10];
    const float* b_ef  = (const float*)d_in[11];
    const int* node_idx = (const int*)d_in[12];
    const int* edge_idx = (const int*)d_in[13];

    const int V = in_sizes[0] / D;   // 100000
    const int E = in_sizes[1] / D;   // 40000
    const int I = in_sizes[12];      // 600000

    float* vfeat_out = (float*)d_out;                  // [V, D]
    float* efeat_out = (float*)d_out + (size_t)V * D;  // [E, D]
    float* acc_e = vfeat_out;  // E*D <= V*D; dead before gather2 writes here

    // ---- workspace layout (ints, all 16B-aligned slices) ----
    int* cnt_e = (int*)d_ws;          // [E]
    int* cnt_v = cnt_e + E;           // [V]  (adjacent -> single memset)
    int* off_e = cnt_v + V;           // [E]
    int* off_v = off_e + E;           // [V]
    int* cur_e = off_v + V;           // [E]
    int* cur_v = cur_e + E;           // [V]
    int* bsum_e = cur_v + V;          // [64]
    int* bsum_v = bsum_e + 64;        // [64]
    int* sorted_n = bsum_v + 64;      // [I] node srcs grouped by edge
    int* sorted_e = sorted_n + I;     // [I] edge srcs grouped by node
    size_t ws_needed = (size_t)(3 * (E + V) + 128 + 2 * I) * sizeof(int);

    const int inc_blocks = (I + 255) / 256;

    if (ws_size < ws_needed) {
        // fallback: atomic scatter path (round-1)
        const int sb = (I * 32 + 255) / 256;
        hipMemsetAsync(acc_e, 0, (size_t)E * D * sizeof(float), stream);
        scatter_kernel<<<sb, 256, 0, stream>>>(vfeat, vrw, ers, node_idx, edge_idx, acc_e, I);
        rowgemm_kernel<0><<<(E + 63) / 64, 256, 0, stream>>>(efeat, W_ef, b_ef, efeat_out, E);
        rowgemm_kernel<1><<<(E + 63) / 64, 256, 0, stream>>>(acc_e, W_ve, b_ve, efeat_out, E);
        hipMemsetAsync(vfeat_out, 0, (size_t)V * D * sizeof(float), stream);
        scatter_kernel<<<sb, 256, 0, stream>>>(efeat_out, erw, vrs, edge_idx, node_idx, vfeat_out, I);
        rowgemm_kernel<2><<<(V + 63) / 64, 256, 0, stream>>>(vfeat_out, W_ev, b_ev, vfeat_out, V);
        return;
    }

    // ---- CSR build (both directions) ----
    hipMemsetAsync(cnt_e, 0, (size_t)(E + V) * sizeof(int), stream);
    hist2_kernel<<<inc_blocks, 256, 0, stream>>>(node_idx, edge_idx, cnt_e, cnt_v, I);

    const int nbE = (E + SCAN_CHUNK - 1) / SCAN_CHUNK;   // 10
    const int nbV = (V + SCAN_CHUNK - 1) / SCAN_CHUNK;   // 25
    scan_block_kernel<<<nbE, 1024, 0, stream>>>(cnt_e, off_e, bsum_e, E);
    scan_block_kernel<<<1, 1024, 0, stream>>>(bsum_e, bsum_e, nullptr, nbE);
    scan_add_kernel<<<(E / 4 + 255) / 256, 256, 0, stream>>>(off_e, bsum_e, E);
    scan_block_kernel<<<nbV, 1024, 0, stream>>>(cnt_v, off_v, bsum_v, V);
    scan_block_kernel<<<1, 1024, 0, stream>>>(bsum_v, bsum_v, nullptr, nbV);
    scan_add_kernel<<<(V / 4 + 255) / 256, 256, 0, stream>>>(off_v, bsum_v, V);

    hipMemcpyAsync(cur_e, off_e, (size_t)E * sizeof(int), hipMemcpyDeviceToDevice, stream);
    hipMemcpyAsync(cur_v, off_v, (size_t)V * sizeof(int), hipMemcpyDeviceToDevice, stream);
    permute2_kernel<<<inc_blocks, 256, 0, stream>>>(node_idx, edge_idx, cur_e, cur_v,
                                                    sorted_n, sorted_e, I);

    // ---- g1: nodes -> hyperedges ----
    gather_kernel<<<(E + 3) / 4, 256, 0, stream>>>(vfeat, vrw, ers, sorted_n, off_e, cnt_e,
                                                   acc_e, E);
    rowgemm_kernel<0><<<(E + 63) / 64, 256, 0, stream>>>(efeat, W_ef, b_ef, efeat_out, E);
    rowgemm_kernel<1><<<(E + 63) / 64, 256, 0, stream>>>(acc_e, W_ve, b_ve, efeat_out, E);

    // ---- g2: hyperedges -> nodes ----
    gather_kernel<<<(V + 3) / 4, 256, 0, stream>>>(efeat_out, erw, vrs, sorted_e, off_v, cnt_v,
                                                   vfeat_out, V);
    rowgemm_kernel<2><<<(V + 63) / 64, 256, 0, stream>>>(vfeat_out, W_ev, b_ev, vfeat_out, V);
}

// Round 3
// 297.794 us; speedup vs baseline: 7.2964x; 1.4843x over previous
//
#include <hip/hip_runtime.h>

#define D 128
#define SCAN_CHUNK 4096   // elements per scan block (1024 threads x 4)

// ---------------------------------------------------------------------------
// Fallback atomic scatter (round-1) — used only if ws_size too small.
// ---------------------------------------------------------------------------
__global__ void __launch_bounds__(256) scatter_kernel(
    const float* __restrict__ feat, const float* __restrict__ w_num,
    const float* __restrict__ w_den, const int* __restrict__ src_idx,
    const int* __restrict__ dst_idx, float* __restrict__ acc, int n_inc)
{
    int gid = blockIdx.x * 256 + threadIdx.x;
    int inc = gid >> 5;
    if (inc >= n_inc) return;
    int c = (gid & 31) << 2;
    int s = src_idx[inc];
    int t = dst_idx[inc];
    float w = w_num[s] / w_den[t];
    float4 v = *reinterpret_cast<const float4*>(feat + (size_t)s * D + c);
    float* dst = acc + (size_t)t * D + c;
    atomicAdd(dst + 0, w * v.x);
    atomicAdd(dst + 1, w * v.y);
    atomicAdd(dst + 2, w * v.z);
    atomicAdd(dst + 3, w * v.w);
}

// ---------------------------------------------------------------------------
// Histogram + rank capture (one atomic stream, ranks stored coalesced).
// cnt is the CONCATENATED histogram: cnt[0..E) edges, cnt[E..E+V) nodes.
// ---------------------------------------------------------------------------
__global__ void __launch_bounds__(256) hist_rank_kernel(
    const int* __restrict__ node_idx, const int* __restrict__ edge_idx,
    int* __restrict__ cnt, int* __restrict__ rank_e, int* __restrict__ rank_v,
    int E, int n)
{
    int i = blockIdx.x * 256 + threadIdx.x;
    if (i >= n) return;
    int nv = node_idx[i], ev = edge_idx[i];
    rank_e[i] = atomicAdd(&cnt[ev], 1);
    rank_v[i] = atomicAdd(&cnt[E + nv], 1);
}

// Per-block exclusive scan (1024 thr x 4 elems); block total -> blocksums.
__global__ void __launch_bounds__(1024) scan_block_kernel(
    const int* __restrict__ in, int* __restrict__ out,
    int* __restrict__ blocksums, int n)
{
    __shared__ int lds[1024];
    const int tid = threadIdx.x;
    const int idx = blockIdx.x * SCAN_CHUNK + tid * 4;
    int4 v = make_int4(0, 0, 0, 0);
    if (idx + 3 < n) v = *reinterpret_cast<const int4*>(in + idx);
    else {
        if (idx + 0 < n) v.x = in[idx + 0];
        if (idx + 1 < n) v.y = in[idx + 1];
        if (idx + 2 < n) v.z = in[idx + 2];
        if (idx + 3 < n) v.w = in[idx + 3];
    }
    lds[tid] = v.x + v.y + v.z + v.w;
    __syncthreads();
    for (int off = 1; off < 1024; off <<= 1) {
        int t = lds[tid];
        int u = (tid >= off) ? lds[tid - off] : 0;
        __syncthreads();
        lds[tid] = t + u;
        __syncthreads();
    }
    int excl = tid ? lds[tid - 1] : 0;
    if (blocksums && tid == 1023) blocksums[blockIdx.x] = lds[1023];
    int4 o;
    o.x = excl;
    o.y = o.x + v.x;
    o.z = o.y + v.y;
    o.w = o.z + v.z;
    if (idx + 3 < n) *reinterpret_cast<int4*>(out + idx) = o;
    else {
        if (idx + 0 < n) out[idx + 0] = o.x;
        if (idx + 1 < n) out[idx + 1] = o.y;
        if (idx + 2 < n) out[idx + 2] = o.z;
        if (idx + 3 < n) out[idx + 3] = o.w;
    }
}

__global__ void __launch_bounds__(256) scan_add_kernel(
    int* __restrict__ out, const int* __restrict__ bsums, int n)
{
    int idx = (blockIdx.x * 256 + threadIdx.x) * 4;
    if (idx >= n) return;
    int add = bsums[idx / SCAN_CHUNK];
    if (idx + 3 < n) {
        int4 v = *reinterpret_cast<int4*>(out + idx);
        v.x += add; v.y += add; v.z += add; v.w += add;
        *reinterpret_cast<int4*>(out + idx) = v;
    } else {
        for (int k = 0; k < 4 && idx + k < n; ++k) out[idx + k] += add;
    }
}

// ---------------------------------------------------------------------------
// Placement: atomic-free scatter into CSR order (both directions).
// off is the exclusive scan of the concatenated cnt; node segment starts
// within sorted_e are off[E+n] - I  (off[E] == I by construction).
// ---------------------------------------------------------------------------
__global__ void __launch_bounds__(256) place_kernel(
    const int* __restrict__ node_idx, const int* __restrict__ edge_idx,
    const int* __restrict__ rank_e, const int* __restrict__ rank_v,
    const int* __restrict__ off,
    int* __restrict__ sorted_n, int* __restrict__ sorted_e,
    int E, int I)
{
    int i = blockIdx.x * 256 + threadIdx.x;
    if (i >= I) return;
    int nv = node_idx[i], ev = edge_idx[i];
    sorted_n[off[ev] + rank_e[i]] = nv;
    sorted_e[off[E + nv] - I + rank_v[i]] = ev;
}

// ---------------------------------------------------------------------------
// gather-sum: 32 lanes per destination row (float4/lane), 8 rows per block,
// 2-way unrolled segment loop (2 row-reads in flight per half-wave).
// out[r][:] = ( sum w_num[src] * feat[src][:] ) / w_den[r]; writes every row.
// ---------------------------------------------------------------------------
__global__ void __launch_bounds__(256) gather_kernel(
    const float* __restrict__ feat,       // [n_src, D]
    const float* __restrict__ w_num,      // [n_src]
    const float* __restrict__ w_den,      // [n_dst]
    const int*   __restrict__ sorted_src, // [I] grouped by dst
    const int*   __restrict__ off,        // [n_dst] segment starts (+base)
    const int*   __restrict__ cnt,        // [n_dst] segment lengths
    int base,
    float*       __restrict__ out,        // [n_dst, D]
    int n_dst)
{
    int row = blockIdx.x * 8 + (threadIdx.x >> 5);
    if (row >= n_dst) return;
    int c = (threadIdx.x & 31) << 2;
    const int* sp = sorted_src + off[row] + base;
    int n = cnt[row];
    float inv = 1.0f / w_den[row];
    float ax = 0.f, ay = 0.f, az = 0.f, aw = 0.f;
    int i = 0;
    for (; i + 2 <= n; i += 2) {
        int s0 = sp[i], s1 = sp[i + 1];
        float w0 = w_num[s0], w1 = w_num[s1];
        float4 f0 = *reinterpret_cast<const float4*>(feat + (size_t)s0 * D + c);
        float4 f1 = *reinterpret_cast<const float4*>(feat + (size_t)s1 * D + c);
        ax = fmaf(w0, f0.x, ax); ay = fmaf(w0, f0.y, ay);
        az = fmaf(w0, f0.z, az); aw = fmaf(w0, f0.w, aw);
        ax = fmaf(w1, f1.x, ax); ay = fmaf(w1, f1.y, ay);
        az = fmaf(w1, f1.z, az); aw = fmaf(w1, f1.w, aw);
    }
    if (i < n) {
        int s0 = sp[i];
        float w0 = w_num[s0];
        float4 f0 = *reinterpret_cast<const float4*>(feat + (size_t)s0 * D + c);
        ax = fmaf(w0, f0.x, ax); ay = fmaf(w0, f0.y, ay);
        az = fmaf(w0, f0.z, az); aw = fmaf(w0, f0.w, aw);
    }
    float4 o = make_float4(ax * inv, ay * inv, az * inv, aw * inv);
    *reinterpret_cast<float4*>(out + (size_t)row * D + c) = o;
}

// ---------------------------------------------------------------------------
// row-wise GEMM: out_row = f(in_row @ W^T + bias).
// MODE 0: out = x ; MODE 2: out = relu(x) (in==out ok: tile staged first)
// ---------------------------------------------------------------------------
template <int MODE>
__global__ void __launch_bounds__(256) rowgemm_kernel(
    const float* __restrict__ in, const float* __restrict__ W,
    const float* __restrict__ bias, float* __restrict__ out, int nrows)
{
    __shared__ float A[64][D + 4];
    __shared__ float Bt[32][D + 4];

    const int tid = threadIdx.x;
    const int r0  = blockIdx.x * 64;
    const int tx  = tid & 15;
    const int gr  = tid >> 4;

    #pragma unroll
    for (int it = 0; it < 8; ++it) {
        int e = tid + it * 256;
        int row = e >> 5;
        int c4 = (e & 31) << 2;
        int grow = r0 + row;
        float4 v = make_float4(0.f, 0.f, 0.f, 0.f);
        if (grow < nrows)
            v = *reinterpret_cast<const float4*>(in + (size_t)grow * D + c4);
        *reinterpret_cast<float4*>(&A[row][c4]) = v;
    }

    float acc[4][8];
    #pragma unroll
    for (int i = 0; i < 4; ++i)
        #pragma unroll
        for (int j = 0; j < 8; ++j) acc[i][j] = 0.f;

    for (int kt = 0; kt < 4; ++kt) {
        __syncthreads();
        #pragma unroll
        for (int it = 0; it < 4; ++it) {
            int e = tid + it * 256;
            int j = e >> 3;
            int kq = (e & 7) << 2;
            float4 w4 = *reinterpret_cast<const float4*>(W + (size_t)j * D + kt * 32 + kq);
            Bt[kq + 0][j] = w4.x;
            Bt[kq + 1][j] = w4.y;
            Bt[kq + 2][j] = w4.z;
            Bt[kq + 3][j] = w4.w;
        }
        __syncthreads();

        #pragma unroll 4
        for (int kk = 0; kk < 32; ++kk) {
            int k = kt * 32 + kk;
            float a[4], b[8];
            #pragma unroll
            for (int i = 0; i < 4; ++i) a[i] = A[4 * gr + i][k];
            #pragma unroll
            for (int j = 0; j < 8; ++j) b[j] = Bt[kk][tx + 16 * j];
            #pragma unroll
            for (int i = 0; i < 4; ++i)
                #pragma unroll
                for (int j = 0; j < 8; ++j)
                    acc[i][j] = fmaf(a[i], b[j], acc[i][j]);
        }
    }

    float bv[8];
    #pragma unroll
    for (int j = 0; j < 8; ++j) bv[j] = bias[tx + 16 * j];

    #pragma unroll
    for (int i = 0; i < 4; ++i) {
        int row = r0 + 4 * gr + i;
        if (row >= nrows) continue;
        #pragma unroll
        for (int j = 0; j < 8; ++j) {
            int col = tx + 16 * j;
            float x = acc[i][j] + bv[j];
            size_t o = (size_t)row * D + col;
            if (MODE == 0) out[o] = x;
            if (MODE == 2) out[o] = fmaxf(x, 0.f);
        }
    }
}

// ---------------------------------------------------------------------------
// dual GEMM for the edge update:
// out = (inL @ WL^T + bL) + relu(inR @ WR^T + bR), same 64-row tiling.
// ---------------------------------------------------------------------------
__global__ void __launch_bounds__(256) dualgemm_kernel(
    const float* __restrict__ inL, const float* __restrict__ WL,
    const float* __restrict__ bL,
    const float* __restrict__ inR, const float* __restrict__ WR,
    const float* __restrict__ bR,
    float* __restrict__ out, int nrows)
{
    __shared__ float A[64][D + 4];
    __shared__ float Bt[32][D + 4];

    const int tid = threadIdx.x;
    const int r0  = blockIdx.x * 64;
    const int tx  = tid & 15;
    const int gr  = tid >> 4;

    float acc0[4][8], acc1[4][8];
    #pragma unroll
    for (int i = 0; i < 4; ++i)
        #pragma unroll
        for (int j = 0; j < 8; ++j) { acc0[i][j] = 0.f; acc1[i][j] = 0.f; }

    for (int pass = 0; pass < 2; ++pass) {
        const float* in = pass ? inR : inL;
        const float* W  = pass ? WR  : WL;

        __syncthreads();   // protect A/Bt from previous pass's readers
        #pragma unroll
        for (int it = 0; it < 8; ++it) {
            int e = tid + it * 256;
            int row = e >> 5;
            int c4 = (e & 31) << 2;
            int grow = r0 + row;
            float4 v = make_float4(0.f, 0.f, 0.f, 0.f);
            if (grow < nrows)
                v = *reinterpret_cast<const float4*>(in + (size_t)grow * D + c4);
            *reinterpret_cast<float4*>(&A[row][c4]) = v;
        }

        for (int kt = 0; kt < 4; ++kt) {
            __syncthreads();
            #pragma unroll
            for (int it = 0; it < 4; ++it) {
                int e = tid + it * 256;
                int j = e >> 3;
                int kq = (e & 7) << 2;
                float4 w4 = *reinterpret_cast<const float4*>(W + (size_t)j * D + kt * 32 + kq);
                Bt[kq + 0][j] = w4.x;
                Bt[kq + 1][j] = w4.y;
                Bt[kq + 2][j] = w4.z;
                Bt[kq + 3][j] = w4.w;
            }
            __syncthreads();

            #pragma unroll 4
            for (int kk = 0; kk < 32; ++kk) {
                int k = kt * 32 + kk;
                float a[4], b[8];
                #pragma unroll
                for (int i = 0; i < 4; ++i) a[i] = A[4 * gr + i][k];
                #pragma unroll
                for (int j = 0; j < 8; ++j) b[j] = Bt[kk][tx + 16 * j];
                if (pass == 0) {
                    #pragma unroll
                    for (int i = 0; i < 4; ++i)
                        #pragma unroll
                        for (int j = 0; j < 8; ++j)
                            acc0[i][j] = fmaf(a[i], b[j], acc0[i][j]);
                } else {
                    #pragma unroll
                    for (int i = 0; i < 4; ++i)
                        #pragma unroll
                        for (int j = 0; j < 8; ++j)
                            acc1[i][j] = fmaf(a[i], b[j], acc1[i][j]);
                }
            }
        }
    }

    float bvL[8], bvR[8];
    #pragma unroll
    for (int j = 0; j < 8; ++j) {
        bvL[j] = bL[tx + 16 * j];
        bvR[j] = bR[tx + 16 * j];
    }

    #pragma unroll
    for (int i = 0; i < 4; ++i) {
        int row = r0 + 4 * gr + i;
        if (row >= nrows) continue;
        #pragma unroll
        for (int j = 0; j < 8; ++j) {
            int col = tx + 16 * j;
            float x = (acc0[i][j] + bvL[j]) + fmaxf(acc1[i][j] + bvR[j], 0.f);
            out[(size_t)row * D + col] = x;
        }
    }
}

// ---------------------------------------------------------------------------
extern "C" void kernel_launch(void* const* d_in, const int* in_sizes, int n_in,
                              void* d_out, int out_size, void* d_ws, size_t ws_size,
                              hipStream_t stream)
{
    const float* vfeat = (const float*)d_in[0];
    const float* efeat = (const float*)d_in[1];
    const float* vrw   = (const float*)d_in[2];
    const float* vrs   = (const float*)d_in[3];
    const float* erw   = (const float*)d_in[4];
    const float* ers   = (const float*)d_in[5];
    const float* W_ve  = (const float*)d_in[6];
    const float* b_ve  = (const float*)d_in[7];
    const float* W_ev  = (const float*)d_in[8];
    const float* b_ev  = (const float*)d_in[9];
    const float* W_ef  = (const float*)d_in[10];
    const float* b_ef  = (const float*)d_in[11];
    const int* node_idx = (const int*)d_in[12];
    const int* edge_idx = (const int*)d_in[13];

    const int V = in_sizes[0] / D;   // 100000
    const int E = in_sizes[1] / D;   // 40000
    const int I = in_sizes[12];      // 600000
    const int EV = E + V;

    float* vfeat_out = (float*)d_out;                  // [V, D]
    float* efeat_out = (float*)d_out + (size_t)V * D;  // [E, D]
    float* acc_e = vfeat_out;  // E*D <= V*D; dead before gather2 writes here

    // ---- workspace layout (ints) ----
    int* cnt_cat  = (int*)d_ws;          // [E+V] edges then nodes
    int* off_cat  = cnt_cat + EV;        // [E+V] exclusive scan of cnt_cat
    int* bsum     = off_cat + EV;        // [64]
    int* rank_e   = bsum + 64;           // [I]
    int* rank_v   = rank_e + I;          // [I]
    int* sorted_n = rank_v + I;          // [I] node srcs grouped by edge
    int* sorted_e = sorted_n + I;        // [I] edge srcs grouped by node
    size_t ws_needed = ((size_t)2 * EV + 64 + (size_t)4 * I) * sizeof(int);

    const int inc_blocks = (I + 255) / 256;

    if (ws_size < ws_needed) {
        // fallback: atomic scatter path (round-1)
        const int sb = (I * 32 + 255) / 256;
        hipMemsetAsync(acc_e, 0, (size_t)E * D * sizeof(float), stream);
        scatter_kernel<<<sb, 256, 0, stream>>>(vfeat, vrw, ers, node_idx, edge_idx, acc_e, I);
        rowgemm_kernel<0><<<(E + 63) / 64, 256, 0, stream>>>(efeat, W_ef, b_ef, efeat_out, E);
        dualgemm_kernel<<<(E + 63) / 64, 256, 0, stream>>>(efeat, W_ef, b_ef,
                                                           acc_e, W_ve, b_ve, efeat_out, E);
        hipMemsetAsync(vfeat_out, 0, (size_t)V * D * sizeof(float), stream);
        scatter_kernel<<<sb, 256, 0, stream>>>(efeat_out, erw, vrs, edge_idx, node_idx, vfeat_out, I);
        rowgemm_kernel<2><<<(V + 63) / 64, 256, 0, stream>>>(vfeat_out, W_ev, b_ev, vfeat_out, V);
        return;
    }

    // ---- CSR build: hist+rank -> scan -> atomic-free place ----
    hipMemsetAsync(cnt_cat, 0, (size_t)EV * sizeof(int), stream);
    hist_rank_kernel<<<inc_blocks, 256, 0, stream>>>(node_idx, edge_idx, cnt_cat,
                                                     rank_e, rank_v, E, I);

    const int nb = (EV + SCAN_CHUNK - 1) / SCAN_CHUNK;   // 35
    scan_block_kernel<<<nb, 1024, 0, stream>>>(cnt_cat, off_cat, bsum, EV);
    scan_block_kernel<<<1, 1024, 0, stream>>>(bsum, bsum, nullptr, nb);
    scan_add_kernel<<<(EV / 4 + 255) / 256, 256, 0, stream>>>(off_cat, bsum, EV);

    place_kernel<<<inc_blocks, 256, 0, stream>>>(node_idx, edge_idx, rank_e, rank_v,
                                                 off_cat, sorted_n, sorted_e, E, I);

    // ---- g1: nodes -> hyperedges ----
    gather_kernel<<<(E + 7) / 8, 256, 0, stream>>>(vfeat, vrw, ers, sorted_n,
                                                   off_cat, cnt_cat, 0, acc_e, E);
    // efeat_out = (efeat @ W_ef^T + b_ef) + relu(acc_e @ W_ve^T + b_ve)
    dualgemm_kernel<<<(E + 63) / 64, 256, 0, stream>>>(efeat, W_ef, b_ef,
                                                       acc_e, W_ve, b_ve, efeat_out, E);

    // ---- g2: hyperedges -> nodes ----
    gather_kernel<<<(V + 7) / 8, 256, 0, stream>>>(efeat_out, erw, vrs, sorted_e,
                                                   off_cat + E, cnt_cat + E, -I,
                                                   vfeat_out, V);
    rowgemm_kernel<2><<<(V + 63) / 64, 256, 0, stream>>>(vfeat_out, W_ev, b_ev, vfeat_out, V);
}

// Round 4
// 238.876 us; speedup vs baseline: 9.0960x; 1.2466x over previous
//
#include <hip/hip_runtime.h>

#define D 128
#define SCAN_CHUNK 4096   // elements per scan block (1024 threads x 4)

typedef __attribute__((ext_vector_type(8))) short   bf16x8;
typedef __attribute__((ext_vector_type(4))) float   f32x4;
typedef __attribute__((ext_vector_type(4))) unsigned short us4;

#define LDSP (D + 8)      // bf16 LDS row pitch: 136 elems = 272 B (bank-safe)

__device__ __forceinline__ unsigned short f2bf(float x) {
    union { float f; unsigned u; } v; v.f = x;
    unsigned r = v.u + 0x7fffu + ((v.u >> 16) & 1u);   // round-to-nearest-even
    return (unsigned short)(r >> 16);
}

// ---------------------------------------------------------------------------
// Fallback atomic scatter — used only if ws_size too small.
// ---------------------------------------------------------------------------
__global__ void __launch_bounds__(256) scatter_kernel(
    const float* __restrict__ feat, const float* __restrict__ w_num,
    const float* __restrict__ w_den, const int* __restrict__ src_idx,
    const int* __restrict__ dst_idx, float* __restrict__ acc, int n_inc)
{
    int gid = blockIdx.x * 256 + threadIdx.x;
    int inc = gid >> 5;
    if (inc >= n_inc) return;
    int c = (gid & 31) << 2;
    int s = src_idx[inc];
    int t = dst_idx[inc];
    float w = w_num[s] / w_den[t];
    float4 v = *reinterpret_cast<const float4*>(feat + (size_t)s * D + c);
    float* dst = acc + (size_t)t * D + c;
    atomicAdd(dst + 0, w * v.x);
    atomicAdd(dst + 1, w * v.y);
    atomicAdd(dst + 2, w * v.z);
    atomicAdd(dst + 3, w * v.w);
}

// ---------------------------------------------------------------------------
// Histogram + rank capture. cnt concatenated: [0..E) edges, [E..E+V) nodes.
// ---------------------------------------------------------------------------
__global__ void __launch_bounds__(256) hist_rank_kernel(
    const int* __restrict__ node_idx, const int* __restrict__ edge_idx,
    int* __restrict__ cnt, int* __restrict__ rank_e, int* __restrict__ rank_v,
    int E, int n)
{
    int i = blockIdx.x * 256 + threadIdx.x;
    if (i >= n) return;
    int nv = node_idx[i], ev = edge_idx[i];
    rank_e[i] = atomicAdd(&cnt[ev], 1);
    rank_v[i] = atomicAdd(&cnt[E + nv], 1);
}

// Per-block exclusive scan (1024 thr x 4 elems); block total -> blocksums.
__global__ void __launch_bounds__(1024) scan_block_kernel(
    const int* __restrict__ in, int* __restrict__ out,
    int* __restrict__ blocksums, int n)
{
    __shared__ int lds[1024];
    const int tid = threadIdx.x;
    const int idx = blockIdx.x * SCAN_CHUNK + tid * 4;
    int4 v = make_int4(0, 0, 0, 0);
    if (idx + 3 < n) v = *reinterpret_cast<const int4*>(in + idx);
    else {
        if (idx + 0 < n) v.x = in[idx + 0];
        if (idx + 1 < n) v.y = in[idx + 1];
        if (idx + 2 < n) v.z = in[idx + 2];
        if (idx + 3 < n) v.w = in[idx + 3];
    }
    lds[tid] = v.x + v.y + v.z + v.w;
    __syncthreads();
    for (int off = 1; off < 1024; off <<= 1) {
        int t = lds[tid];
        int u = (tid >= off) ? lds[tid - off] : 0;
        __syncthreads();
        lds[tid] = t + u;
        __syncthreads();
    }
    int excl = tid ? lds[tid - 1] : 0;
    if (blocksums && tid == 1023) blocksums[blockIdx.x] = lds[1023];
    int4 o;
    o.x = excl;
    o.y = o.x + v.x;
    o.z = o.y + v.y;
    o.w = o.z + v.z;
    if (idx + 3 < n) *reinterpret_cast<int4*>(out + idx) = o;
    else {
        if (idx + 0 < n) out[idx + 0] = o.x;
        if (idx + 1 < n) out[idx + 1] = o.y;
        if (idx + 2 < n) out[idx + 2] = o.z;
        if (idx + 3 < n) out[idx + 3] = o.w;
    }
}

__global__ void __launch_bounds__(256) scan_add_kernel(
    int* __restrict__ out, const int* __restrict__ bsums, int n)
{
    int idx = (blockIdx.x * 256 + threadIdx.x) * 4;
    if (idx >= n) return;
    int add = bsums[idx / SCAN_CHUNK];
    if (idx + 3 < n) {
        int4 v = *reinterpret_cast<int4*>(out + idx);
        v.x += add; v.y += add; v.z += add; v.w += add;
        *reinterpret_cast<int4*>(out + idx) = v;
    } else {
        for (int k = 0; k < 4 && idx + k < n; ++k) out[idx + k] += add;
    }
}

// ---------------------------------------------------------------------------
// Placement: atomic-free scatter into CSR order (both directions).
// ---------------------------------------------------------------------------
__global__ void __launch_bounds__(256) place_kernel(
    const int* __restrict__ node_idx, const int* __restrict__ edge_idx,
    const int* __restrict__ rank_e, const int* __restrict__ rank_v,
    const int* __restrict__ off,
    int* __restrict__ sorted_n, int* __restrict__ sorted_e,
    int E, int I)
{
    int i = blockIdx.x * 256 + threadIdx.x;
    if (i >= I) return;
    int nv = node_idx[i], ev = edge_idx[i];
    sorted_n[off[ev] + rank_e[i]] = nv;
    sorted_e[off[E + nv] - I + rank_v[i]] = ev;
}

// ---------------------------------------------------------------------------
// gather-sum: 32 lanes per destination row (float4/lane), 8 rows per block.
// out[r][:] = ( sum w_num[src] * feat[src][:] ) / w_den[r]; writes every row.
// ---------------------------------------------------------------------------
__global__ void __launch_bounds__(256) gather_kernel(
    const float* __restrict__ feat, const float* __restrict__ w_num,
    const float* __restrict__ w_den, const int* __restrict__ sorted_src,
    const int* __restrict__ off, const int* __restrict__ cnt, int base,
    float* __restrict__ out, int n_dst)
{
    int row = blockIdx.x * 8 + (threadIdx.x >> 5);
    if (row >= n_dst) return;
    int c = (threadIdx.x & 31) << 2;
    const int* sp = sorted_src + off[row] + base;
    int n = cnt[row];
    float inv = 1.0f / w_den[row];
    float ax = 0.f, ay = 0.f, az = 0.f, aw = 0.f;
    int i = 0;
    for (; i + 2 <= n; i += 2) {
        int s0 = sp[i], s1 = sp[i + 1];
        float w0 = w_num[s0], w1 = w_num[s1];
        float4 f0 = *reinterpret_cast<const float4*>(feat + (size_t)s0 * D + c);
        float4 f1 = *reinterpret_cast<const float4*>(feat + (size_t)s1 * D + c);
        ax = fmaf(w0, f0.x, ax); ay = fmaf(w0, f0.y, ay);
        az = fmaf(w0, f0.z, az); aw = fmaf(w0, f0.w, aw);
        ax = fmaf(w1, f1.x, ax); ay = fmaf(w1, f1.y, ay);
        az = fmaf(w1, f1.z, az); aw = fmaf(w1, f1.w, aw);
    }
    if (i < n) {
        int s0 = sp[i];
        float w0 = w_num[s0];
        float4 f0 = *reinterpret_cast<const float4*>(feat + (size_t)s0 * D + c);
        ax = fmaf(w0, f0.x, ax); ay = fmaf(w0, f0.y, ay);
        az = fmaf(w0, f0.z, az); aw = fmaf(w0, f0.w, aw);
    }
    float4 o = make_float4(ax * inv, ay * inv, az * inv, aw * inv);
    *reinterpret_cast<float4*>(out + (size_t)row * D + c) = o;
}

// ---------------------------------------------------------------------------
// LDS staging helpers for MFMA GEMMs (f32 global -> bf16 LDS).
// A tile: 64 rows x 128 cols; W: 128 x 128. Row pitch LDSP=136 bf16.
// ---------------------------------------------------------------------------
__device__ __forceinline__ void stage_A64(
    unsigned short* A_lds, const float* __restrict__ in, int r0, int nrows, int tid)
{
    #pragma unroll
    for (int it = 0; it < 8; ++it) {
        int e   = tid + it * 256;       // 0..2047
        int row = e >> 5;
        int c4  = (e & 31) << 2;
        int grow = r0 + row;
        float4 v = make_float4(0.f, 0.f, 0.f, 0.f);
        if (grow < nrows)
            v = *reinterpret_cast<const float4*>(in + (size_t)grow * D + c4);
        us4 b = { f2bf(v.x), f2bf(v.y), f2bf(v.z), f2bf(v.w) };
        *reinterpret_cast<us4*>(A_lds + row * LDSP + c4) = b;
    }
}

__device__ __forceinline__ void stage_W(
    unsigned short* W_lds, const float* __restrict__ W, int tid)
{
    #pragma unroll
    for (int it = 0; it < 16; ++it) {
        int e   = tid + it * 256;       // 0..4095
        int row = e >> 5;
        int c4  = (e & 31) << 2;
        float4 v = *reinterpret_cast<const float4*>(W + (size_t)row * D + c4);
        us4 b = { f2bf(v.x), f2bf(v.y), f2bf(v.z), f2bf(v.w) };
        *reinterpret_cast<us4*>(W_lds + row * LDSP + c4) = b;
    }
}

// MFMA compute: wave handles 16 rows x 128 cols. acc[ct] over 8 col-tiles.
__device__ __forceinline__ void mfma_16x128(
    const unsigned short* A_lds, const unsigned short* W_lds,
    int wv, int lane, f32x4 acc[8])
{
    const int lr = lane & 15;
    const int lk = (lane >> 4) << 3;   // 0,8,16,24
    const unsigned short* arow = A_lds + (wv * 16 + lr) * LDSP;
    #pragma unroll
    for (int kt = 0; kt < 4; ++kt) {
        bf16x8 af = *reinterpret_cast<const bf16x8*>(arow + kt * 32 + lk);
        #pragma unroll
        for (int ct = 0; ct < 8; ++ct) {
            bf16x8 bfr = *reinterpret_cast<const bf16x8*>(
                W_lds + (ct * 16 + lr) * LDSP + kt * 32 + lk);
            acc[ct] = __builtin_amdgcn_mfma_f32_16x16x32_bf16(af, bfr, acc[ct], 0, 0, 0);
        }
    }
}

// ---------------------------------------------------------------------------
// MFMA row-GEMM: out = f(in @ W^T + bias). MODE 0: identity, MODE 2: relu.
// In-place safe (in==out): A tile fully staged before any store.
// ---------------------------------------------------------------------------
template <int MODE>
__global__ void __launch_bounds__(256) mfma_gemm_kernel(
    const float* __restrict__ in, const float* __restrict__ W,
    const float* __restrict__ bias, float* __restrict__ out, int nrows)
{
    __shared__ unsigned short A_lds[64 * LDSP];
    __shared__ unsigned short W_lds[D * LDSP];

    const int tid  = threadIdx.x;
    const int r0   = blockIdx.x * 64;
    const int wv   = tid >> 6;
    const int lane = tid & 63;

    stage_A64(A_lds, in, r0, nrows, tid);
    stage_W(W_lds, W, tid);
    __syncthreads();

    f32x4 acc[8];
    #pragma unroll
    for (int ct = 0; ct < 8; ++ct) acc[ct] = (f32x4){0.f, 0.f, 0.f, 0.f};
    mfma_16x128(A_lds, W_lds, wv, lane, acc);

    const int lr = lane & 15;
    const int rb = r0 + wv * 16 + ((lane >> 4) << 2);
    #pragma unroll
    for (int ct = 0; ct < 8; ++ct) {
        int col = ct * 16 + lr;
        float bv = bias[col];
        #pragma unroll
        for (int i = 0; i < 4; ++i) {
            int row = rb + i;
            if (row >= nrows) continue;
            float x = acc[ct][i] + bv;
            if (MODE == 2) x = fmaxf(x, 0.f);
            out[(size_t)row * D + col] = x;
        }
    }
}

// ---------------------------------------------------------------------------
// MFMA dual GEMM: out = (inL @ WL^T + bL) + relu(inR @ WR^T + bR).
// ---------------------------------------------------------------------------
__global__ void __launch_bounds__(256) mfma_dualgemm_kernel(
    const float* __restrict__ inL, const float* __restrict__ WL,
    const float* __restrict__ bL,
    const float* __restrict__ inR, const float* __restrict__ WR,
    const float* __restrict__ bR,
    float* __restrict__ out, int nrows)
{
    __shared__ unsigned short A_lds[64 * LDSP];
    __shared__ unsigned short W_lds[D * LDSP];

    const int tid  = threadIdx.x;
    const int r0   = blockIdx.x * 64;
    const int wv   = tid >> 6;
    const int lane = tid & 63;

    f32x4 acc0[8], acc1[8];
    #pragma unroll
    for (int ct = 0; ct < 8; ++ct) {
        acc0[ct] = (f32x4){0.f, 0.f, 0.f, 0.f};
        acc1[ct] = (f32x4){0.f, 0.f, 0.f, 0.f};
    }

    // pass 0: L
    stage_A64(A_lds, inL, r0, nrows, tid);
    stage_W(W_lds, WL, tid);
    __syncthreads();
    mfma_16x128(A_lds, W_lds, wv, lane, acc0);
    __syncthreads();   // all reads done before restage

    // pass 1: R
    stage_A64(A_lds, inR, r0, nrows, tid);
    stage_W(W_lds, WR, tid);
    __syncthreads();
    mfma_16x128(A_lds, W_lds, wv, lane, acc1);

    const int lr = lane & 15;
    const int rb = r0 + wv * 16 + ((lane >> 4) << 2);
    #pragma unroll
    for (int ct = 0; ct < 8; ++ct) {
        int col = ct * 16 + lr;
        float bvL = bL[col];
        float bvR = bR[col];
        #pragma unroll
        for (int i = 0; i < 4; ++i) {
            int row = rb + i;
            if (row >= nrows) continue;
            float x = (acc0[ct][i] + bvL) + fmaxf(acc1[ct][i] + bvR, 0.f);
            out[(size_t)row * D + col] = x;
        }
    }
}

// ---------------------------------------------------------------------------
extern "C" void kernel_launch(void* const* d_in, const int* in_sizes, int n_in,
                              void* d_out, int out_size, void* d_ws, size_t ws_size,
                              hipStream_t stream)
{
    const float* vfeat = (const float*)d_in[0];
    const float* efeat = (const float*)d_in[1];
    const float* vrw   = (const float*)d_in[2];
    const float* vrs   = (const float*)d_in[3];
    const float* erw   = (const float*)d_in[4];
    const float* ers   = (const float*)d_in[5];
    const float* W_ve  = (const float*)d_in[6];
    const float* b_ve  = (const float*)d_in[7];
    const float* W_ev  = (const float*)d_in[8];
    const float* b_ev  = (const float*)d_in[9];
    const float* W_ef  = (const float*)d_in[10];
    const float* b_ef  = (const float*)d_in[11];
    const int* node_idx = (const int*)d_in[12];
    const int* edge_idx = (const int*)d_in[13];

    const int V = in_sizes[0] / D;   // 100000
    const int E = in_sizes[1] / D;   // 40000
    const int I = in_sizes[12];      // 600000
    const int EV = E + V;

    float* vfeat_out = (float*)d_out;                  // [V, D]
    float* efeat_out = (float*)d_out + (size_t)V * D;  // [E, D]
    float* acc_e = vfeat_out;  // E*D <= V*D; dead before gather2 writes here

    // ---- workspace layout (ints) ----
    int* cnt_cat  = (int*)d_ws;          // [E+V]
    int* off_cat  = cnt_cat + EV;        // [E+V]
    int* bsum     = off_cat + EV;        // [64]
    int* rank_e   = bsum + 64;           // [I]
    int* rank_v   = rank_e + I;          // [I]
    int* sorted_n = rank_v + I;          // [I]
    int* sorted_e = sorted_n + I;        // [I]
    size_t ws_needed = ((size_t)2 * EV + 64 + (size_t)4 * I) * sizeof(int);

    const int inc_blocks = (I + 255) / 256;

    if (ws_size < ws_needed) {
        const int sb = (I * 32 + 255) / 256;
        hipMemsetAsync(acc_e, 0, (size_t)E * D * sizeof(float), stream);
        scatter_kernel<<<sb, 256, 0, stream>>>(vfeat, vrw, ers, node_idx, edge_idx, acc_e, I);
        mfma_dualgemm_kernel<<<(E + 63) / 64, 256, 0, stream>>>(
            efeat, W_ef, b_ef, acc_e, W_ve, b_ve, efeat_out, E);
        hipMemsetAsync(vfeat_out, 0, (size_t)V * D * sizeof(float), stream);
        scatter_kernel<<<sb, 256, 0, stream>>>(efeat_out, erw, vrs, edge_idx, node_idx, vfeat_out, I);
        mfma_gemm_kernel<2><<<(V + 63) / 64, 256, 0, stream>>>(vfeat_out, W_ev, b_ev, vfeat_out, V);
        return;
    }

    // ---- CSR build: hist+rank -> scan -> atomic-free place ----
    hipMemsetAsync(cnt_cat, 0, (size_t)EV * sizeof(int), stream);
    hist_rank_kernel<<<inc_blocks, 256, 0, stream>>>(node_idx, edge_idx, cnt_cat,
                                                     rank_e, rank_v, E, I);

    const int nb = (EV + SCAN_CHUNK - 1) / SCAN_CHUNK;   // 35
    scan_block_kernel<<<nb, 1024, 0, stream>>>(cnt_cat, off_cat, bsum, EV);
    scan_block_kernel<<<1, 1024, 0, stream>>>(bsum, bsum, nullptr, nb);
    scan_add_kernel<<<(EV / 4 + 255) / 256, 256, 0, stream>>>(off_cat, bsum, EV);

    place_kernel<<<inc_blocks, 256, 0, stream>>>(node_idx, edge_idx, rank_e, rank_v,
                                                 off_cat, sorted_n, sorted_e, E, I);

    // ---- g1: nodes -> hyperedges ----
    gather_kernel<<<(E + 7) / 8, 256, 0, stream>>>(vfeat, vrw, ers, sorted_n,
                                                   off_cat, cnt_cat, 0, acc_e, E);
    // efeat_out = (efeat @ W_ef^T + b_ef) + relu(acc_e @ W_ve^T + b_ve)
    mfma_dualgemm_kernel<<<(E + 63) / 64, 256, 0, stream>>>(
        efeat, W_ef, b_ef, acc_e, W_ve, b_ve, efeat_out, E);

    // ---- g2: hyperedges -> nodes ----
    gather_kernel<<<(V + 7) / 8, 256, 0, stream>>>(efeat_out, erw, vrs, sorted_e,
                                                   off_cat + E, cnt_cat + E, -I,
                                                   vfeat_out, V);
    mfma_gemm_kernel<2><<<(V + 63) / 64, 256, 0, stream>>>(vfeat_out, W_ev, b_ev, vfeat_out, V);
}

// Round 5
// 216.492 us; speedup vs baseline: 10.0365x; 1.1034x over previous
//
#include <hip/hip_runtime.h>

#define D 128
#define SCAN_CHUNK 4096   // elements per scan block (1024 threads x 4)

typedef __attribute__((ext_vector_type(8))) short   bf16x8;
typedef __attribute__((ext_vector_type(4))) float   f32x4;
typedef __attribute__((ext_vector_type(4))) unsigned short us4;

#define LDSP (D + 8)      // bf16 LDS row pitch: 136 elems = 272 B (2-way max)

__device__ __forceinline__ unsigned short f2bf(float x) {
    union { float f; unsigned u; } v; v.f = x;
    unsigned r = v.u + 0x7fffu + ((v.u >> 16) & 1u);   // round-to-nearest-even
    return (unsigned short)(r >> 16);
}
__device__ __forceinline__ float bf2f(unsigned short u) {
    union { unsigned u; float f; } v; v.u = ((unsigned)u) << 16; return v.f;
}

// ---------------------------------------------------------------------------
// f32 -> bf16 bulk convert (grid-stride, float4 in / us4 out)
// ---------------------------------------------------------------------------
__global__ void __launch_bounds__(256) cvt_f32_bf16_kernel(
    const float* __restrict__ in, unsigned short* __restrict__ out, int n4)
{
    int stride = gridDim.x * 256;
    for (int i = blockIdx.x * 256 + threadIdx.x; i < n4; i += stride) {
        float4 v = *reinterpret_cast<const float4*>(in + (size_t)i * 4);
        us4 b = { f2bf(v.x), f2bf(v.y), f2bf(v.z), f2bf(v.w) };
        *reinterpret_cast<us4*>(out + (size_t)i * 4) = b;
    }
}

// ---------------------------------------------------------------------------
// Fallback atomic scatter — used only if ws_size too small for CSR.
// ---------------------------------------------------------------------------
__global__ void __launch_bounds__(256) scatter_kernel(
    const float* __restrict__ feat, const float* __restrict__ w_num,
    const float* __restrict__ w_den, const int* __restrict__ src_idx,
    const int* __restrict__ dst_idx, float* __restrict__ acc, int n_inc)
{
    int gid = blockIdx.x * 256 + threadIdx.x;
    int inc = gid >> 5;
    if (inc >= n_inc) return;
    int c = (gid & 31) << 2;
    int s = src_idx[inc];
    int t = dst_idx[inc];
    float w = w_num[s] / w_den[t];
    float4 v = *reinterpret_cast<const float4*>(feat + (size_t)s * D + c);
    float* dst = acc + (size_t)t * D + c;
    atomicAdd(dst + 0, w * v.x);
    atomicAdd(dst + 1, w * v.y);
    atomicAdd(dst + 2, w * v.z);
    atomicAdd(dst + 3, w * v.w);
}

// ---------------------------------------------------------------------------
// Histogram + rank capture, 2 incidences per thread (4 atomics in flight).
// cnt concatenated: [0..E) edges, [E..E+V) nodes.
// ---------------------------------------------------------------------------
__global__ void __launch_bounds__(256) hist_rank_kernel(
    const int* __restrict__ node_idx, const int* __restrict__ edge_idx,
    int* __restrict__ cnt, int* __restrict__ rank_e, int* __restrict__ rank_v,
    int E, int n)
{
    int half = (n + 1) >> 1;
    int i = blockIdx.x * 256 + threadIdx.x;
    if (i >= half) return;
    int nv0 = node_idx[i], ev0 = edge_idx[i];
    int j = i + half;
    if (j < n) {
        int nv1 = node_idx[j], ev1 = edge_idx[j];
        int a = atomicAdd(&cnt[ev0], 1);
        int b = atomicAdd(&cnt[ev1], 1);
        int c = atomicAdd(&cnt[E + nv0], 1);
        int d = atomicAdd(&cnt[E + nv1], 1);
        rank_e[i] = a; rank_e[j] = b;
        rank_v[i] = c; rank_v[j] = d;
    } else {
        rank_e[i] = atomicAdd(&cnt[ev0], 1);
        rank_v[i] = atomicAdd(&cnt[E + nv0], 1);
    }
}

// Per-block exclusive scan (1024 thr x 4 elems); block total -> blocksums.
// Consumers add bsum[bin >> 12] themselves (no scan_add pass).
__global__ void __launch_bounds__(1024) scan_block_kernel(
    const int* __restrict__ in, int* __restrict__ out,
    int* __restrict__ blocksums, int n)
{
    __shared__ int lds[1024];
    const int tid = threadIdx.x;
    const int idx = blockIdx.x * SCAN_CHUNK + tid * 4;
    int4 v = make_int4(0, 0, 0, 0);
    if (idx + 3 < n) v = *reinterpret_cast<const int4*>(in + idx);
    else {
        if (idx + 0 < n) v.x = in[idx + 0];
        if (idx + 1 < n) v.y = in[idx + 1];
        if (idx + 2 < n) v.z = in[idx + 2];
        if (idx + 3 < n) v.w = in[idx + 3];
    }
    lds[tid] = v.x + v.y + v.z + v.w;
    __syncthreads();
    for (int off = 1; off < 1024; off <<= 1) {
        int t = lds[tid];
        int u = (tid >= off) ? lds[tid - off] : 0;
        __syncthreads();
        lds[tid] = t + u;
        __syncthreads();
    }
    int excl = tid ? lds[tid - 1] : 0;
    if (blocksums && tid == 1023) blocksums[blockIdx.x] = lds[1023];
    int4 o;
    o.x = excl;
    o.y = o.x + v.x;
    o.z = o.y + v.y;
    o.w = o.z + v.z;
    if (idx + 3 < n) *reinterpret_cast<int4*>(out + idx) = o;
    else {
        if (idx + 0 < n) out[idx + 0] = o.x;
        if (idx + 1 < n) out[idx + 1] = o.y;
        if (idx + 2 < n) out[idx + 2] = o.z;
        if (idx + 3 < n) out[idx + 3] = o.w;
    }
}

// ---------------------------------------------------------------------------
// Placement: atomic-free scatter into CSR order (both directions).
// Global segment start = off[bin] + bsum[bin>>12]; node side shifted by -I.
// ---------------------------------------------------------------------------
__global__ void __launch_bounds__(256) place_kernel(
    const int* __restrict__ node_idx, const int* __restrict__ edge_idx,
    const int* __restrict__ rank_e, const int* __restrict__ rank_v,
    const int* __restrict__ off, const int* __restrict__ bsum,
    int* __restrict__ sorted_n, int* __restrict__ sorted_e,
    int E, int I)
{
    int i = blockIdx.x * 256 + threadIdx.x;
    if (i >= I) return;
    int nv = node_idx[i], ev = edge_idx[i];
    sorted_n[off[ev] + bsum[ev >> 12] + rank_e[i]] = nv;
    int b2 = E + nv;
    sorted_e[off[b2] + bsum[b2 >> 12] - I + rank_v[i]] = ev;
}

// ---------------------------------------------------------------------------
// gather-sum: 32 lanes per destination row (4 cols/lane), 8 rows per block,
// 2-way unrolled. IN_BF: feat rows are bf16. OUT_BF: write bf16 rows.
// out[r][:] = ( sum w_num[src] * feat[src][:] ) / w_den[r]; writes every row.
// ---------------------------------------------------------------------------
template <int IN_BF>
__device__ __forceinline__ float4 ldrow4(const void* feat, int s, int c) {
    if constexpr (IN_BF) {
        us4 v = *reinterpret_cast<const us4*>(
            (const unsigned short*)feat + (size_t)s * D + c);
        return make_float4(bf2f(v[0]), bf2f(v[1]), bf2f(v[2]), bf2f(v[3]));
    } else {
        return *reinterpret_cast<const float4*>((const float*)feat + (size_t)s * D + c);
    }
}

template <int IN_BF, int OUT_BF>
__global__ void __launch_bounds__(256) gather_seg_kernel(
    const void* __restrict__ feat, const float* __restrict__ w_num,
    const float* __restrict__ w_den, const int* __restrict__ sorted_src,
    const int* __restrict__ off, const int* __restrict__ bsum,
    const int* __restrict__ cnt, int binBase, int sortBase,
    void* __restrict__ out, int n_dst)
{
    int row = blockIdx.x * 8 + (threadIdx.x >> 5);
    if (row >= n_dst) return;
    int c = (threadIdx.x & 31) << 2;
    int bin = binBase + row;
    const int* sp = sorted_src + (off[bin] + bsum[bin >> 12] + sortBase);
    int n = cnt[bin];
    float inv = 1.0f / w_den[row];
    float a0 = 0.f, a1 = 0.f, a2 = 0.f, a3 = 0.f;
    int i = 0;
    for (; i + 2 <= n; i += 2) {
        int s0 = sp[i], s1 = sp[i + 1];
        float w0 = w_num[s0], w1 = w_num[s1];
        float4 f0 = ldrow4<IN_BF>(feat, s0, c);
        float4 f1 = ldrow4<IN_BF>(feat, s1, c);
        a0 = fmaf(w0, f0.x, a0); a1 = fmaf(w0, f0.y, a1);
        a2 = fmaf(w0, f0.z, a2); a3 = fmaf(w0, f0.w, a3);
        a0 = fmaf(w1, f1.x, a0); a1 = fmaf(w1, f1.y, a1);
        a2 = fmaf(w1, f1.z, a2); a3 = fmaf(w1, f1.w, a3);
    }
    if (i < n) {
        int s0 = sp[i];
        float w0 = w_num[s0];
        float4 f0 = ldrow4<IN_BF>(feat, s0, c);
        a0 = fmaf(w0, f0.x, a0); a1 = fmaf(w0, f0.y, a1);
        a2 = fmaf(w0, f0.z, a2); a3 = fmaf(w0, f0.w, a3);
    }
    if constexpr (OUT_BF) {
        us4 o = { f2bf(a0 * inv), f2bf(a1 * inv), f2bf(a2 * inv), f2bf(a3 * inv) };
        *reinterpret_cast<us4*>((unsigned short*)out + (size_t)row * D + c) = o;
    } else {
        float4 o = make_float4(a0 * inv, a1 * inv, a2 * inv, a3 * inv);
        *reinterpret_cast<float4*>((float*)out + (size_t)row * D + c) = o;
    }
}

// ---------------------------------------------------------------------------
// LDS staging helpers for MFMA GEMMs.
// ---------------------------------------------------------------------------
__device__ __forceinline__ void stage_A64(
    unsigned short* A_lds, const float* __restrict__ in, int r0, int nrows, int tid)
{
    #pragma unroll
    for (int it = 0; it < 8; ++it) {
        int e   = tid + it * 256;       // 0..2047 float4 chunks
        int row = e >> 5;
        int c4  = (e & 31) << 2;
        int grow = r0 + row;
        float4 v = make_float4(0.f, 0.f, 0.f, 0.f);
        if (grow < nrows)
            v = *reinterpret_cast<const float4*>(in + (size_t)grow * D + c4);
        us4 b = { f2bf(v.x), f2bf(v.y), f2bf(v.z), f2bf(v.w) };
        *reinterpret_cast<us4*>(A_lds + row * LDSP + c4) = b;
    }
}

__device__ __forceinline__ void stage_A64_bf(
    unsigned short* A_lds, const unsigned short* __restrict__ in,
    int r0, int nrows, int tid)
{
    #pragma unroll
    for (int it = 0; it < 4; ++it) {
        int e   = tid + it * 256;       // 0..1023 bf16x8 chunks
        int row = e >> 4;
        int c8  = (e & 15) << 3;
        int grow = r0 + row;
        bf16x8 v;
        #pragma unroll
        for (int j = 0; j < 8; ++j) v[j] = 0;
        if (grow < nrows)
            v = *reinterpret_cast<const bf16x8*>(in + (size_t)grow * D + c8);
        *reinterpret_cast<bf16x8*>(A_lds + row * LDSP + c8) = v;
    }
}

__device__ __forceinline__ void stage_W(
    unsigned short* W_lds, const float* __restrict__ W, int tid)
{
    #pragma unroll
    for (int it = 0; it < 16; ++it) {
        int e   = tid + it * 256;       // 0..4095 float4 chunks
        int row = e >> 5;
        int c4  = (e & 31) << 2;
        float4 v = *reinterpret_cast<const float4*>(W + (size_t)row * D + c4);
        us4 b = { f2bf(v.x), f2bf(v.y), f2bf(v.z), f2bf(v.w) };
        *reinterpret_cast<us4*>(W_lds + row * LDSP + c4) = b;
    }
}

// MFMA compute: wave handles 16 rows x 128 cols. acc[ct] over 8 col-tiles.
__device__ __forceinline__ void mfma_16x128(
    const unsigned short* A_lds, const unsigned short* W_lds,
    int wv, int lane, f32x4 acc[8])
{
    const int lr = lane & 15;
    const int lk = (lane >> 4) << 3;   // 0,8,16,24
    const unsigned short* arow = A_lds + (wv * 16 + lr) * LDSP;
    #pragma unroll
    for (int kt = 0; kt < 4; ++kt) {
        bf16x8 af = *reinterpret_cast<const bf16x8*>(arow + kt * 32 + lk);
        #pragma unroll
        for (int ct = 0; ct < 8; ++ct) {
            bf16x8 bfr = *reinterpret_cast<const bf16x8*>(
                W_lds + (ct * 16 + lr) * LDSP + kt * 32 + lk);
            acc[ct] = __builtin_amdgcn_mfma_f32_16x16x32_bf16(af, bfr, acc[ct], 0, 0, 0);
        }
    }
}

// ---------------------------------------------------------------------------
// MFMA row-GEMM: out = f(in @ W^T + bias). MODE 0: identity, MODE 2: relu.
// In-place safe (in==out): A tile fully staged before any store.
// ---------------------------------------------------------------------------
template <int MODE>
__global__ void __launch_bounds__(256) mfma_gemm_kernel(
    const float* __restrict__ in, const float* __restrict__ W,
    const float* __restrict__ bias, float* __restrict__ out, int nrows)
{
    __shared__ unsigned short A_lds[64 * LDSP];
    __shared__ unsigned short W_lds[D * LDSP];

    const int tid  = threadIdx.x;
    const int r0   = blockIdx.x * 64;
    const int wv   = tid >> 6;
    const int lane = tid & 63;

    stage_A64(A_lds, in, r0, nrows, tid);
    stage_W(W_lds, W, tid);
    __syncthreads();

    f32x4 acc[8];
    #pragma unroll
    for (int ct = 0; ct < 8; ++ct) acc[ct] = (f32x4){0.f, 0.f, 0.f, 0.f};
    mfma_16x128(A_lds, W_lds, wv, lane, acc);

    const int lr = lane & 15;
    const int rb = r0 + wv * 16 + ((lane >> 4) << 2);
    #pragma unroll
    for (int ct = 0; ct < 8; ++ct) {
        int col = ct * 16 + lr;
        float bv = bias[col];
        #pragma unroll
        for (int i = 0; i < 4; ++i) {
            int row = rb + i;
            if (row >= nrows) continue;
            float x = acc[ct][i] + bv;
            if (MODE == 2) x = fmaxf(x, 0.f);
            out[(size_t)row * D + col] = x;
        }
    }
}

// ---------------------------------------------------------------------------
// MFMA dual GEMM: out = (inL @ WL^T + bL) + relu(inR @ WR^T + bR).
// RBF: R input rows are bf16.
// ---------------------------------------------------------------------------
template <int RBF>
__global__ void __launch_bounds__(256) mfma_dualgemm_kernel(
    const float* __restrict__ inL, const float* __restrict__ WL,
    const float* __restrict__ bL,
    const void*  __restrict__ inR, const float* __restrict__ WR,
    const float* __restrict__ bR,
    float* __restrict__ out, int nrows)
{
    __shared__ unsigned short A_lds[64 * LDSP];
    __shared__ unsigned short W_lds[D * LDSP];

    const int tid  = threadIdx.x;
    const int r0   = blockIdx.x * 64;
    const int wv   = tid >> 6;
    const int lane = tid & 63;

    f32x4 acc0[8], acc1[8];
    #pragma unroll
    for (int ct = 0; ct < 8; ++ct) {
        acc0[ct] = (f32x4){0.f, 0.f, 0.f, 0.f};
        acc1[ct] = (f32x4){0.f, 0.f, 0.f, 0.f};
    }

    // pass 0: L (f32)
    stage_A64(A_lds, inL, r0, nrows, tid);
    stage_W(W_lds, WL, tid);
    __syncthreads();
    mfma_16x128(A_lds, W_lds, wv, lane, acc0);
    __syncthreads();   // all reads done before restage

    // pass 1: R
    if constexpr (RBF)
        stage_A64_bf(A_lds, (const unsigned short*)inR, r0, nrows, tid);
    else
        stage_A64(A_lds, (const float*)inR, r0, nrows, tid);
    stage_W(W_lds, WR, tid);
    __syncthreads();
    mfma_16x128(A_lds, W_lds, wv, lane, acc1);

    const int lr = lane & 15;
    const int rb = r0 + wv * 16 + ((lane >> 4) << 2);
    #pragma unroll
    for (int ct = 0; ct < 8; ++ct) {
        int col = ct * 16 + lr;
        float bvL = bL[col];
        float bvR = bR[col];
        #pragma unroll
        for (int i = 0; i < 4; ++i) {
            int row = rb + i;
            if (row >= nrows) continue;
            float x = (acc0[ct][i] + bvL) + fmaxf(acc1[ct][i] + bvR, 0.f);
            out[(size_t)row * D + col] = x;
        }
    }
}

// ---------------------------------------------------------------------------
extern "C" void kernel_launch(void* const* d_in, const int* in_sizes, int n_in,
                              void* d_out, int out_size, void* d_ws, size_t ws_size,
                              hipStream_t stream)
{
    const float* vfeat = (const float*)d_in[0];
    const float* efeat = (const float*)d_in[1];
    const float* vrw   = (const float*)d_in[2];
    const float* vrs   = (const float*)d_in[3];
    const float* erw   = (const float*)d_in[4];
    const float* ers   = (const float*)d_in[5];
    const float* W_ve  = (const float*)d_in[6];
    const float* b_ve  = (const float*)d_in[7];
    const float* W_ev  = (const float*)d_in[8];
    const float* b_ev  = (const float*)d_in[9];
    const float* W_ef  = (const float*)d_in[10];
    const float* b_ef  = (const float*)d_in[11];
    const int* node_idx = (const int*)d_in[12];
    const int* edge_idx = (const int*)d_in[13];

    const int V = in_sizes[0] / D;   // 100000
    const int E = in_sizes[1] / D;   // 40000
    const int I = in_sizes[12];      // 600000
    const int EV = E + V;

    float* vfeat_out = (float*)d_out;                  // [V, D]
    float* efeat_out = (float*)d_out + (size_t)V * D;  // [E, D]

    // ---- workspace layout (ints, then optional bf16 mirror) ----
    int* cnt_cat  = (int*)d_ws;          // [E+V]
    int* off_cat  = cnt_cat + EV;        // [E+V]
    int* bsum     = off_cat + EV;        // [64]
    int* rank_e   = bsum + 64;           // [I]
    int* rank_v   = rank_e + I;          // [I]
    int* sorted_n = rank_v + I;          // [I]
    int* sorted_e = sorted_n + I;        // [I]
    size_t ws_ints = ((size_t)2 * EV + 64 + (size_t)4 * I) * sizeof(int);
    unsigned short* eout_bf = (unsigned short*)((char*)d_ws + ws_ints); // [E*D]
    size_t ws_tierA = ws_ints + (size_t)E * D * sizeof(unsigned short);

    const int inc_blocks  = (I + 255) / 256;
    const int half_blocks = (((I + 1) >> 1) + 255) / 256;
    const int nb = (EV + SCAN_CHUNK - 1) / SCAN_CHUNK;   // 35

    if (ws_size < ws_ints) {
        // ---- tier C: atomic fallback ----
        float* acc_e = vfeat_out;
        const int sb = (I * 32 + 255) / 256;
        hipMemsetAsync(acc_e, 0, (size_t)E * D * sizeof(float), stream);
        scatter_kernel<<<sb, 256, 0, stream>>>(vfeat, vrw, ers, node_idx, edge_idx, acc_e, I);
        mfma_dualgemm_kernel<0><<<(E + 63) / 64, 256, 0, stream>>>(
            efeat, W_ef, b_ef, acc_e, W_ve, b_ve, efeat_out, E);
        hipMemsetAsync(vfeat_out, 0, (size_t)V * D * sizeof(float), stream);
        scatter_kernel<<<sb, 256, 0, stream>>>(efeat_out, erw, vrs, edge_idx, node_idx, vfeat_out, I);
        mfma_gemm_kernel<2><<<(V + 63) / 64, 256, 0, stream>>>(vfeat_out, W_ev, b_ev, vfeat_out, V);
        return;
    }

    // ---- CSR build (shared by tiers A/B) ----
    hipMemsetAsync(cnt_cat, 0, (size_t)EV * sizeof(int), stream);
    hist_rank_kernel<<<half_blocks, 256, 0, stream>>>(node_idx, edge_idx, cnt_cat,
                                                      rank_e, rank_v, E, I);
    scan_block_kernel<<<nb, 1024, 0, stream>>>(cnt_cat, off_cat, bsum, EV);
    scan_block_kernel<<<1, 1024, 0, stream>>>(bsum, bsum, nullptr, nb);
    place_kernel<<<inc_blocks, 256, 0, stream>>>(node_idx, edge_idx, rank_e, rank_v,
                                                 off_cat, bsum, sorted_n, sorted_e, E, I);

    if (ws_size >= ws_tierA) {
        // ---- tier A: bf16 gather tables ----
        // scratch inside the (not-yet-live) vfeat_out region of d_out:
        unsigned short* vfeat_bf = (unsigned short*)d_out;              // [V*D]
        unsigned short* acc_e_bf = vfeat_bf + (size_t)V * D;            // [E*D]
        // (V*D + E*D) bf16 = 35.84 MB <= V*D f32 = 51.2 MB; dead before gather2.

        cvt_f32_bf16_kernel<<<2048, 256, 0, stream>>>(vfeat, vfeat_bf, V * D / 4);

        // g1: nodes -> hyperedges (bf16 table, bf16 out)
        gather_seg_kernel<1, 1><<<(E + 7) / 8, 256, 0, stream>>>(
            vfeat_bf, vrw, ers, sorted_n, off_cat, bsum, cnt_cat, 0, 0, acc_e_bf, E);
        // efeat_out = (efeat @ W_ef^T + b_ef) + relu(acc_e @ W_ve^T + b_ve)
        mfma_dualgemm_kernel<1><<<(E + 63) / 64, 256, 0, stream>>>(
            efeat, W_ef, b_ef, acc_e_bf, W_ve, b_ve, efeat_out, E);
        // bf16 mirror of efeat_out for the node-direction gather
        cvt_f32_bf16_kernel<<<2048, 256, 0, stream>>>(efeat_out, eout_bf, E * D / 4);

        // g2: hyperedges -> nodes (bf16 table ~10 MB, f32 out into vfeat_out)
        gather_seg_kernel<1, 0><<<(V + 7) / 8, 256, 0, stream>>>(
            eout_bf, erw, vrs, sorted_e, off_cat, bsum, cnt_cat, E, -I, vfeat_out, V);
        mfma_gemm_kernel<2><<<(V + 63) / 64, 256, 0, stream>>>(
            vfeat_out, W_ev, b_ev, vfeat_out, V);
    } else {
        // ---- tier B: f32 gather (round-4 behavior, scan_add folded) ----
        float* acc_e = vfeat_out;   // dead before gather2 writes here
        gather_seg_kernel<0, 0><<<(E + 7) / 8, 256, 0, stream>>>(
            vfeat, vrw, ers, sorted_n, off_cat, bsum, cnt_cat, 0, 0, acc_e, E);
        mfma_dualgemm_kernel<0><<<(E + 63) / 64, 256, 0, stream>>>(
            efeat, W_ef, b_ef, acc_e, W_ve, b_ve, efeat_out, E);
        gather_seg_kernel<0, 0><<<(V + 7) / 8, 256, 0, stream>>>(
            efeat_out, erw, vrs, sorted_e, off_cat, bsum, cnt_cat, E, -I, vfeat_out, V);
        mfma_gemm_kernel<2><<<(V + 63) / 64, 256, 0, stream>>>(
            vfeat_out, W_ev, b_ev, vfeat_out, V);
    }
}

// Round 6
// 187.442 us; speedup vs baseline: 11.5920x; 1.1550x over previous
//
#include <hip/hip_runtime.h>

#define D 128
#define SCAN_CHUNK 4096   // elements per scan block (1024 threads x 4)

typedef __attribute__((ext_vector_type(8))) short   bf16x8;
typedef __attribute__((ext_vector_type(4))) float   f32x4;
typedef __attribute__((ext_vector_type(4))) unsigned short us4;

#define LDSP (D + 8)      // bf16 LDS row pitch: 136 elems = 272 B (2-way max)

__device__ __forceinline__ unsigned short f2bf(float x) {
    union { float f; unsigned u; } v; v.f = x;
    unsigned r = v.u + 0x7fffu + ((v.u >> 16) & 1u);   // round-to-nearest-even
    return (unsigned short)(r >> 16);
}
__device__ __forceinline__ float bf2f(unsigned short u) {
    union { unsigned u; float f; } v; v.u = ((unsigned)u) << 16; return v.f;
}

// ---------------------------------------------------------------------------
// Fallback atomic scatter — used only if ws_size too small for CSR.
// ---------------------------------------------------------------------------
__global__ void __launch_bounds__(256) scatter_kernel(
    const float* __restrict__ feat, const float* __restrict__ w_num,
    const float* __restrict__ w_den, const int* __restrict__ src_idx,
    const int* __restrict__ dst_idx, float* __restrict__ acc, int n_inc)
{
    int gid = blockIdx.x * 256 + threadIdx.x;
    int inc = gid >> 5;
    if (inc >= n_inc) return;
    int c = (gid & 31) << 2;
    int s = src_idx[inc];
    int t = dst_idx[inc];
    float w = w_num[s] / w_den[t];
    float4 v = *reinterpret_cast<const float4*>(feat + (size_t)s * D + c);
    float* dst = acc + (size_t)t * D + c;
    atomicAdd(dst + 0, w * v.x);
    atomicAdd(dst + 1, w * v.y);
    atomicAdd(dst + 2, w * v.z);
    atomicAdd(dst + 3, w * v.w);
}

// ---------------------------------------------------------------------------
// FAT kernel: blocks [0,HB) do histogram+rank capture (atomic-latency bound);
// blocks [HB,HB+CB) convert vfeat f32 -> bf16 (BW bound) on otherwise-idle CUs.
// cnt concatenated: [0..E) edges, [E..E+V) nodes.
// ---------------------------------------------------------------------------
__global__ void __launch_bounds__(256) fat_hist_cvt_kernel(
    const int* __restrict__ node_idx, const int* __restrict__ edge_idx,
    int* __restrict__ cnt, int* __restrict__ rank_e, int* __restrict__ rank_v,
    int E, int n,
    const float* __restrict__ vf, unsigned short* __restrict__ vf_bf,
    int n4, int HB, int CB)
{
    if ((int)blockIdx.x < HB) {
        int half = (n + 1) >> 1;
        int i = blockIdx.x * 256 + threadIdx.x;
        if (i >= half) return;
        int nv0 = node_idx[i], ev0 = edge_idx[i];
        int j = i + half;
        if (j < n) {
            int nv1 = node_idx[j], ev1 = edge_idx[j];
            int a = atomicAdd(&cnt[ev0], 1);
            int b = atomicAdd(&cnt[ev1], 1);
            int c = atomicAdd(&cnt[E + nv0], 1);
            int d = atomicAdd(&cnt[E + nv1], 1);
            rank_e[i] = a; rank_e[j] = b;
            rank_v[i] = c; rank_v[j] = d;
        } else {
            rank_e[i] = atomicAdd(&cnt[ev0], 1);
            rank_v[i] = atomicAdd(&cnt[E + nv0], 1);
        }
    } else {
        int b = blockIdx.x - HB;
        int stride = CB * 256;
        for (int i = b * 256 + threadIdx.x; i < n4; i += stride) {
            float4 v = *reinterpret_cast<const float4*>(vf + (size_t)i * 4);
            us4 o = { f2bf(v.x), f2bf(v.y), f2bf(v.z), f2bf(v.w) };
            *reinterpret_cast<us4*>(vf_bf + (size_t)i * 4) = o;
        }
    }
}

// Per-block exclusive scan (1024 thr x 4 elems); block total -> blocksums.
// Consumers add bsum[bin >> 12] themselves (no scan_add pass).
__global__ void __launch_bounds__(1024) scan_block_kernel(
    const int* __restrict__ in, int* __restrict__ out,
    int* __restrict__ blocksums, int n)
{
    __shared__ int lds[1024];
    const int tid = threadIdx.x;
    const int idx = blockIdx.x * SCAN_CHUNK + tid * 4;
    int4 v = make_int4(0, 0, 0, 0);
    if (idx + 3 < n) v = *reinterpret_cast<const int4*>(in + idx);
    else {
        if (idx + 0 < n) v.x = in[idx + 0];
        if (idx + 1 < n) v.y = in[idx + 1];
        if (idx + 2 < n) v.z = in[idx + 2];
        if (idx + 3 < n) v.w = in[idx + 3];
    }
    lds[tid] = v.x + v.y + v.z + v.w;
    __syncthreads();
    for (int off = 1; off < 1024; off <<= 1) {
        int t = lds[tid];
        int u = (tid >= off) ? lds[tid - off] : 0;
        __syncthreads();
        lds[tid] = t + u;
        __syncthreads();
    }
    int excl = tid ? lds[tid - 1] : 0;
    if (blocksums && tid == 1023) blocksums[blockIdx.x] = lds[1023];
    int4 o;
    o.x = excl;
    o.y = o.x + v.x;
    o.z = o.y + v.y;
    o.w = o.z + v.z;
    if (idx + 3 < n) *reinterpret_cast<int4*>(out + idx) = o;
    else {
        if (idx + 0 < n) out[idx + 0] = o.x;
        if (idx + 1 < n) out[idx + 1] = o.y;
        if (idx + 2 < n) out[idx + 2] = o.z;
        if (idx + 3 < n) out[idx + 3] = o.w;
    }
}

// ---------------------------------------------------------------------------
// Placement: atomic-free scatter into CSR order (both directions).
// Global segment start = off[bin] + bsum[bin>>12]; node side shifted by -I.
// ---------------------------------------------------------------------------
__global__ void __launch_bounds__(256) place_kernel(
    const int* __restrict__ node_idx, const int* __restrict__ edge_idx,
    const int* __restrict__ rank_e, const int* __restrict__ rank_v,
    const int* __restrict__ off, const int* __restrict__ bsum,
    int* __restrict__ sorted_n, int* __restrict__ sorted_e,
    int E, int I)
{
    int i = blockIdx.x * 256 + threadIdx.x;
    if (i >= I) return;
    int nv = node_idx[i], ev = edge_idx[i];
    sorted_n[off[ev] + bsum[ev >> 12] + rank_e[i]] = nv;
    int b2 = E + nv;
    sorted_e[off[b2] + bsum[b2 >> 12] - I + rank_v[i]] = ev;
}

// ---------------------------------------------------------------------------
// gather-sum: 32 lanes per destination row (4 cols/lane), 8 rows per block,
// 2-way unrolled. IN_BF: feat rows bf16. OUT_BF: bf16 out. BR: +bias, relu.
// out[r][:] = g( (sum w_num[src] * feat[src][:]) / w_den[r] )
// ---------------------------------------------------------------------------
template <int IN_BF>
__device__ __forceinline__ float4 ldrow4(const void* feat, int s, int c) {
    if constexpr (IN_BF) {
        us4 v = *reinterpret_cast<const us4*>(
            (const unsigned short*)feat + (size_t)s * D + c);
        return make_float4(bf2f(v[0]), bf2f(v[1]), bf2f(v[2]), bf2f(v[3]));
    } else {
        return *reinterpret_cast<const float4*>((const float*)feat + (size_t)s * D + c);
    }
}

template <int IN_BF, int OUT_BF, int BR>
__global__ void __launch_bounds__(256) gather_seg_kernel(
    const void* __restrict__ feat, const float* __restrict__ w_num,
    const float* __restrict__ w_den, const int* __restrict__ sorted_src,
    const int* __restrict__ off, const int* __restrict__ bsum,
    const int* __restrict__ cnt, int binBase, int sortBase,
    const float* __restrict__ bias,
    void* __restrict__ out, int n_dst)
{
    int row = blockIdx.x * 8 + (threadIdx.x >> 5);
    if (row >= n_dst) return;
    int c = (threadIdx.x & 31) << 2;
    int bin = binBase + row;
    const int* sp = sorted_src + (off[bin] + bsum[bin >> 12] + sortBase);
    int n = cnt[bin];
    float inv = 1.0f / w_den[row];
    float a0 = 0.f, a1 = 0.f, a2 = 0.f, a3 = 0.f;
    int i = 0;
    for (; i + 2 <= n; i += 2) {
        int s0 = sp[i], s1 = sp[i + 1];
        float w0 = w_num[s0], w1 = w_num[s1];
        float4 f0 = ldrow4<IN_BF>(feat, s0, c);
        float4 f1 = ldrow4<IN_BF>(feat, s1, c);
        a0 = fmaf(w0, f0.x, a0); a1 = fmaf(w0, f0.y, a1);
        a2 = fmaf(w0, f0.z, a2); a3 = fmaf(w0, f0.w, a3);
        a0 = fmaf(w1, f1.x, a0); a1 = fmaf(w1, f1.y, a1);
        a2 = fmaf(w1, f1.z, a2); a3 = fmaf(w1, f1.w, a3);
    }
    if (i < n) {
        int s0 = sp[i];
        float w0 = w_num[s0];
        float4 f0 = ldrow4<IN_BF>(feat, s0, c);
        a0 = fmaf(w0, f0.x, a0); a1 = fmaf(w0, f0.y, a1);
        a2 = fmaf(w0, f0.z, a2); a3 = fmaf(w0, f0.w, a3);
    }
    a0 *= inv; a1 *= inv; a2 *= inv; a3 *= inv;
    if constexpr (BR) {
        float4 bv = *reinterpret_cast<const float4*>(bias + c);
        a0 = fmaxf(a0 + bv.x, 0.f); a1 = fmaxf(a1 + bv.y, 0.f);
        a2 = fmaxf(a2 + bv.z, 0.f); a3 = fmaxf(a3 + bv.w, 0.f);
    }
    if constexpr (OUT_BF) {
        us4 o = { f2bf(a0), f2bf(a1), f2bf(a2), f2bf(a3) };
        *reinterpret_cast<us4*>((unsigned short*)out + (size_t)row * D + c) = o;
    } else {
        float4 o = make_float4(a0, a1, a2, a3);
        *reinterpret_cast<float4*>((float*)out + (size_t)row * D + c) = o;
    }
}

// ---------------------------------------------------------------------------
// LDS staging helpers for MFMA GEMMs.
// ---------------------------------------------------------------------------
__device__ __forceinline__ void stage_A64(
    unsigned short* A_lds, const float* __restrict__ in, int r0, int nrows, int tid)
{
    #pragma unroll
    for (int it = 0; it < 8; ++it) {
        int e   = tid + it * 256;       // 0..2047 float4 chunks
        int row = e >> 5;
        int c4  = (e & 31) << 2;
        int grow = r0 + row;
        float4 v = make_float4(0.f, 0.f, 0.f, 0.f);
        if (grow < nrows)
            v = *reinterpret_cast<const float4*>(in + (size_t)grow * D + c4);
        us4 b = { f2bf(v.x), f2bf(v.y), f2bf(v.z), f2bf(v.w) };
        *reinterpret_cast<us4*>(A_lds + row * LDSP + c4) = b;
    }
}

__device__ __forceinline__ void stage_A64_bf(
    unsigned short* A_lds, const unsigned short* __restrict__ in,
    int r0, int nrows, int tid)
{
    #pragma unroll
    for (int it = 0; it < 4; ++it) {
        int e   = tid + it * 256;       // 0..1023 bf16x8 chunks
        int row = e >> 4;
        int c8  = (e & 15) << 3;
        int grow = r0 + row;
        bf16x8 v;
        #pragma unroll
        for (int j = 0; j < 8; ++j) v[j] = 0;
        if (grow < nrows)
            v = *reinterpret_cast<const bf16x8*>(in + (size_t)grow * D + c8);
        *reinterpret_cast<bf16x8*>(A_lds + row * LDSP + c8) = v;
    }
}

__device__ __forceinline__ void stage_W(
    unsigned short* W_lds, const float* __restrict__ W, int tid)
{
    #pragma unroll
    for (int it = 0; it < 16; ++it) {
        int e   = tid + it * 256;       // 0..4095 float4 chunks
        int row = e >> 5;
        int c4  = (e & 31) << 2;
        float4 v = *reinterpret_cast<const float4*>(W + (size_t)row * D + c4);
        us4 b = { f2bf(v.x), f2bf(v.y), f2bf(v.z), f2bf(v.w) };
        *reinterpret_cast<us4*>(W_lds + row * LDSP + c4) = b;
    }
}

// MFMA compute: wave handles 16 rows x 128 cols. acc[ct] over 8 col-tiles.
__device__ __forceinline__ void mfma_16x128(
    const unsigned short* A_lds, const unsigned short* W_lds,
    int wv, int lane, f32x4 acc[8])
{
    const int lr = lane & 15;
    const int lk = (lane >> 4) << 3;   // 0,8,16,24
    const unsigned short* arow = A_lds + (wv * 16 + lr) * LDSP;
    #pragma unroll
    for (int kt = 0; kt < 4; ++kt) {
        bf16x8 af = *reinterpret_cast<const bf16x8*>(arow + kt * 32 + lk);
        #pragma unroll
        for (int ct = 0; ct < 8; ++ct) {
            bf16x8 bfr = *reinterpret_cast<const bf16x8*>(
                W_lds + (ct * 16 + lr) * LDSP + kt * 32 + lk);
            acc[ct] = __builtin_amdgcn_mfma_f32_16x16x32_bf16(af, bfr, acc[ct], 0, 0, 0);
        }
    }
}

// ---------------------------------------------------------------------------
// MFMA row-GEMM: out = f(in @ W^T + bias). MODE 0: identity, MODE 2: relu.
// In-place safe (in==out). Used by fallback tiers.
// ---------------------------------------------------------------------------
template <int MODE>
__global__ void __launch_bounds__(256) mfma_gemm_kernel(
    const float* __restrict__ in, const float* __restrict__ W,
    const float* __restrict__ bias, float* __restrict__ out, int nrows)
{
    __shared__ unsigned short A_lds[64 * LDSP];
    __shared__ unsigned short W_lds[D * LDSP];

    const int tid  = threadIdx.x;
    const int r0   = blockIdx.x * 64;
    const int wv   = tid >> 6;
    const int lane = tid & 63;

    stage_A64(A_lds, in, r0, nrows, tid);
    stage_W(W_lds, W, tid);
    __syncthreads();

    f32x4 acc[8];
    #pragma unroll
    for (int ct = 0; ct < 8; ++ct) acc[ct] = (f32x4){0.f, 0.f, 0.f, 0.f};
    mfma_16x128(A_lds, W_lds, wv, lane, acc);

    const int lr = lane & 15;
    const int rb = r0 + wv * 16 + ((lane >> 4) << 2);
    #pragma unroll
    for (int ct = 0; ct < 8; ++ct) {
        int col = ct * 16 + lr;
        float bv = bias[col];
        #pragma unroll
        for (int i = 0; i < 4; ++i) {
            int row = rb + i;
            if (row >= nrows) continue;
            float x = acc[ct][i] + bv;
            if (MODE == 2) x = fmaxf(x, 0.f);
            out[(size_t)row * D + col] = x;
        }
    }
}

// ---------------------------------------------------------------------------
// MFMA dual GEMM (fallback tiers): out = (inL@WL^T + bL) + relu(inR@WR^T + bR).
// ---------------------------------------------------------------------------
template <int RBF>
__global__ void __launch_bounds__(256) mfma_dualgemm_kernel(
    const float* __restrict__ inL, const float* __restrict__ WL,
    const float* __restrict__ bL,
    const void*  __restrict__ inR, const float* __restrict__ WR,
    const float* __restrict__ bR,
    float* __restrict__ out, int nrows)
{
    __shared__ unsigned short A_lds[64 * LDSP];
    __shared__ unsigned short W_lds[D * LDSP];

    const int tid  = threadIdx.x;
    const int r0   = blockIdx.x * 64;
    const int wv   = tid >> 6;
    const int lane = tid & 63;

    f32x4 acc0[8], acc1[8];
    #pragma unroll
    for (int ct = 0; ct < 8; ++ct) {
        acc0[ct] = (f32x4){0.f, 0.f, 0.f, 0.f};
        acc1[ct] = (f32x4){0.f, 0.f, 0.f, 0.f};
    }

    stage_A64(A_lds, inL, r0, nrows, tid);
    stage_W(W_lds, WL, tid);
    __syncthreads();
    mfma_16x128(A_lds, W_lds, wv, lane, acc0);
    __syncthreads();

    if constexpr (RBF)
        stage_A64_bf(A_lds, (const unsigned short*)inR, r0, nrows, tid);
    else
        stage_A64(A_lds, (const float*)inR, r0, nrows, tid);
    stage_W(W_lds, WR, tid);
    __syncthreads();
    mfma_16x128(A_lds, W_lds, wv, lane, acc1);

    const int lr = lane & 15;
    const int rb = r0 + wv * 16 + ((lane >> 4) << 2);
    #pragma unroll
    for (int ct = 0; ct < 8; ++ct) {
        int col = ct * 16 + lr;
        float bvL = bL[col];
        float bvR = bR[col];
        #pragma unroll
        for (int i = 0; i < 4; ++i) {
            int row = rb + i;
            if (row >= nrows) continue;
            float x = (acc0[ct][i] + bvL) + fmaxf(acc1[ct][i] + bvR, 0.f);
            out[(size_t)row * D + col] = x;
        }
    }
}

// ---------------------------------------------------------------------------
// TRIPLE GEMM (tier A):
//   eout = (inL @ WL^T + bL) + relu(inR_bf @ WR^T + bR)   -> outE (f32)
//   Z    = eout @ WZ^T                                     -> outZ (bf16)
// Pass 3 restages the register eout tile as bf16 into A_lds.
// ---------------------------------------------------------------------------
__global__ void __launch_bounds__(256) mfma_trigemm_kernel(
    const float* __restrict__ inL, const float* __restrict__ WL,
    const float* __restrict__ bL,
    const unsigned short* __restrict__ inR, const float* __restrict__ WR,
    const float* __restrict__ bR,
    const float* __restrict__ WZ,
    float* __restrict__ outE, unsigned short* __restrict__ outZ, int nrows)
{
    __shared__ unsigned short A_lds[64 * LDSP];
    __shared__ unsigned short W_lds[D * LDSP];

    const int tid  = threadIdx.x;
    const int r0   = blockIdx.x * 64;
    const int wv   = tid >> 6;
    const int lane = tid & 63;
    const int lr   = lane & 15;
    const int lg   = lane >> 4;          // 0..3 row group
    const int rb   = r0 + wv * 16 + (lg << 2);

    f32x4 acc0[8], acc1[8];
    #pragma unroll
    for (int ct = 0; ct < 8; ++ct) {
        acc0[ct] = (f32x4){0.f, 0.f, 0.f, 0.f};
        acc1[ct] = (f32x4){0.f, 0.f, 0.f, 0.f};
    }

    // pass 0: L = efeat (f32) x W_ef
    stage_A64(A_lds, inL, r0, nrows, tid);
    stage_W(W_lds, WL, tid);
    __syncthreads();
    mfma_16x128(A_lds, W_lds, wv, lane, acc0);
    __syncthreads();

    // pass 1: R = acc_e (bf16) x W_ve
    stage_A64_bf(A_lds, inR, r0, nrows, tid);
    stage_W(W_lds, WR, tid);
    __syncthreads();
    mfma_16x128(A_lds, W_lds, wv, lane, acc1);

    // epilogue 1: eout = (acc0+bL) + relu(acc1+bR); store f32; keep values
    float ev[8][4];
    #pragma unroll
    for (int ct = 0; ct < 8; ++ct) {
        int col = ct * 16 + lr;
        float bvL = bL[col];
        float bvR = bR[col];
        #pragma unroll
        for (int i = 0; i < 4; ++i) {
            float x = (acc0[ct][i] + bvL) + fmaxf(acc1[ct][i] + bvR, 0.f);
            ev[ct][i] = x;
            int row = rb + i;
            if (row < nrows) outE[(size_t)row * D + col] = x;
        }
    }

    __syncthreads();   // all pass-1 LDS reads done before restage

    // restage eout tile (bf16) into A_lds: each wave writes its own 16-row slab
    #pragma unroll
    for (int ct = 0; ct < 8; ++ct) {
        int col = ct * 16 + lr;
        #pragma unroll
        for (int i = 0; i < 4; ++i) {
            A_lds[(wv * 16 + (lg << 2) + i) * LDSP + col] = f2bf(ev[ct][i]);
        }
    }
    stage_W(W_lds, WZ, tid);
    __syncthreads();

    // pass 2: Z = eout x W_ev
    f32x4 accZ[8];
    #pragma unroll
    for (int ct = 0; ct < 8; ++ct) accZ[ct] = (f32x4){0.f, 0.f, 0.f, 0.f};
    mfma_16x128(A_lds, W_lds, wv, lane, accZ);

    // epilogue 2: store Z as bf16
    #pragma unroll
    for (int ct = 0; ct < 8; ++ct) {
        int col = ct * 16 + lr;
        #pragma unroll
        for (int i = 0; i < 4; ++i) {
            int row = rb + i;
            if (row < nrows) outZ[(size_t)row * D + col] = f2bf(accZ[ct][i]);
        }
    }
}

// ---------------------------------------------------------------------------
extern "C" void kernel_launch(void* const* d_in, const int* in_sizes, int n_in,
                              void* d_out, int out_size, void* d_ws, size_t ws_size,
                              hipStream_t stream)
{
    const float* vfeat = (const float*)d_in[0];
    const float* efeat = (const float*)d_in[1];
    const float* vrw   = (const float*)d_in[2];
    const float* vrs   = (const float*)d_in[3];
    const float* erw   = (const float*)d_in[4];
    const float* ers   = (const float*)d_in[5];
    const float* W_ve  = (const float*)d_in[6];
    const float* b_ve  = (const float*)d_in[7];
    const float* W_ev  = (const float*)d_in[8];
    const float* b_ev  = (const float*)d_in[9];
    const float* W_ef  = (const float*)d_in[10];
    const float* b_ef  = (const float*)d_in[11];
    const int* node_idx = (const int*)d_in[12];
    const int* edge_idx = (const int*)d_in[13];

    const int V = in_sizes[0] / D;   // 100000
    const int E = in_sizes[1] / D;   // 40000
    const int I = in_sizes[12];      // 600000
    const int EV = E + V;

    float* vfeat_out = (float*)d_out;                  // [V, D]
    float* efeat_out = (float*)d_out + (size_t)V * D;  // [E, D]

    // ---- workspace layout (ints, then bf16 Z table) ----
    int* cnt_cat  = (int*)d_ws;          // [E+V]
    int* off_cat  = cnt_cat + EV;        // [E+V]
    int* bsum     = off_cat + EV;        // [64]
    int* rank_e   = bsum + 64;           // [I]
    int* rank_v   = rank_e + I;          // [I]
    int* sorted_n = rank_v + I;          // [I]
    int* sorted_e = sorted_n + I;        // [I]
    size_t ws_ints = ((size_t)2 * EV + 64 + (size_t)4 * I) * sizeof(int);
    unsigned short* z_bf = (unsigned short*)((char*)d_ws + ws_ints); // [E*D]
    size_t ws_tierA = ws_ints + (size_t)E * D * sizeof(unsigned short);

    const int inc_blocks  = (I + 255) / 256;
    const int half_blocks = (((I + 1) >> 1) + 255) / 256;
    const int nb = (EV + SCAN_CHUNK - 1) / SCAN_CHUNK;   // 35

    if (ws_size < ws_ints) {
        // ---- tier C: atomic fallback ----
        float* acc_e = vfeat_out;
        const int sb = (I * 32 + 255) / 256;
        hipMemsetAsync(acc_e, 0, (size_t)E * D * sizeof(float), stream);
        scatter_kernel<<<sb, 256, 0, stream>>>(vfeat, vrw, ers, node_idx, edge_idx, acc_e, I);
        mfma_dualgemm_kernel<0><<<(E + 63) / 64, 256, 0, stream>>>(
            efeat, W_ef, b_ef, acc_e, W_ve, b_ve, efeat_out, E);
        hipMemsetAsync(vfeat_out, 0, (size_t)V * D * sizeof(float), stream);
        scatter_kernel<<<sb, 256, 0, stream>>>(efeat_out, erw, vrs, edge_idx, node_idx, vfeat_out, I);
        mfma_gemm_kernel<2><<<(V + 63) / 64, 256, 0, stream>>>(vfeat_out, W_ev, b_ev, vfeat_out, V);
        return;
    }

    hipMemsetAsync(cnt_cat, 0, (size_t)EV * sizeof(int), stream);

    if (ws_size >= ws_tierA) {
        // ---- tier A ----
        // bf16 scratch inside the (not-yet-live) vfeat_out region of d_out:
        unsigned short* vfeat_bf = (unsigned short*)d_out;              // [V*D]
        unsigned short* acc_e_bf = vfeat_bf + (size_t)V * D;            // [E*D]
        // 25.6 + 10.2 MB <= 51.2 MB; both dead before gather2 writes vfeat_out.

        const int CB = 1024;
        fat_hist_cvt_kernel<<<half_blocks + CB, 256, 0, stream>>>(
            node_idx, edge_idx, cnt_cat, rank_e, rank_v, E, I,
            vfeat, vfeat_bf, V * D / 4, half_blocks, CB);

        scan_block_kernel<<<nb, 1024, 0, stream>>>(cnt_cat, off_cat, bsum, EV);
        scan_block_kernel<<<1, 1024, 0, stream>>>(bsum, bsum, nullptr, nb);
        place_kernel<<<inc_blocks, 256, 0, stream>>>(node_idx, edge_idx, rank_e, rank_v,
                                                     off_cat, bsum, sorted_n, sorted_e, E, I);

        // g1: nodes -> hyperedges (bf16 table, bf16 out)
        gather_seg_kernel<1, 1, 0><<<(E + 7) / 8, 256, 0, stream>>>(
            vfeat_bf, vrw, ers, sorted_n, off_cat, bsum, cnt_cat, 0, 0,
            nullptr, acc_e_bf, E);

        // eout = (efeat@W_ef^T+b_ef) + relu(acc_e@W_ve^T+b_ve);  Z = eout@W_ev^T
        mfma_trigemm_kernel<<<(E + 63) / 64, 256, 0, stream>>>(
            efeat, W_ef, b_ef, acc_e_bf, W_ve, b_ve, W_ev, efeat_out, z_bf, E);

        // g2: vfeat_out = relu( (sum w * Z[e]) / vrs + b_ev )
        gather_seg_kernel<1, 0, 1><<<(V + 7) / 8, 256, 0, stream>>>(
            z_bf, erw, vrs, sorted_e, off_cat, bsum, cnt_cat, E, -I,
            b_ev, vfeat_out, V);
    } else {
        // ---- tier B: f32 gather path ----
        float* acc_e = vfeat_out;   // dead before gather2 writes here
        fat_hist_cvt_kernel<<<half_blocks, 256, 0, stream>>>(
            node_idx, edge_idx, cnt_cat, rank_e, rank_v, E, I,
            nullptr, nullptr, 0, half_blocks, 1);
        scan_block_kernel<<<nb, 1024, 0, stream>>>(cnt_cat, off_cat, bsum, EV);
        scan_block_kernel<<<1, 1024, 0, stream>>>(bsum, bsum, nullptr, nb);
        place_kernel<<<inc_blocks, 256, 0, stream>>>(node_idx, edge_idx, rank_e, rank_v,
                                                     off_cat, bsum, sorted_n, sorted_e, E, I);
        gather_seg_kernel<0, 0, 0><<<(E + 7) / 8, 256, 0, stream>>>(
            vfeat, vrw, ers, sorted_n, off_cat, bsum, cnt_cat, 0, 0,
            nullptr, acc_e, E);
        mfma_dualgemm_kernel<0><<<(E + 63) / 64, 256, 0, stream>>>(
            efeat, W_ef, b_ef, acc_e, W_ve, b_ve, efeat_out, E);
        gather_seg_kernel<0, 0, 0><<<(V + 7) / 8, 256, 0, stream>>>(
            efeat_out, erw, vrs, sorted_e, off_cat, bsum, cnt_cat, E, -I,
            nullptr, vfeat_out, V);
        mfma_gemm_kernel<2><<<(V + 63) / 64, 256, 0, stream>>>(
            vfeat_out, W_ev, b_ev, vfeat_out, V);
    }
}

// Round 7
// 152.501 us; speedup vs baseline: 14.2480x; 1.2291x over previous
//
#include <hip/hip_runtime.h>

#define D 128
#define SCAN_CHUNK 4096    // elements per scan block (old tier-B path)
#define PART_ELEMS 4096    // incidences per partition block (1024 thr x 4)
#define MAXB 2048          // max buckets per direction (LDS arrays)

typedef __attribute__((ext_vector_type(8))) short   bf16x8;
typedef __attribute__((ext_vector_type(4))) float   f32x4;
typedef __attribute__((ext_vector_type(4))) unsigned short us4;

#define LDSP (D + 8)       // bf16 LDS row pitch: 136 elems = 272 B (2-way max)

__device__ __forceinline__ unsigned short f2bf(float x) {
    union { float f; unsigned u; } v; v.f = x;
    unsigned r = v.u + 0x7fffu + ((v.u >> 16) & 1u);   // round-to-nearest-even
    return (unsigned short)(r >> 16);
}
__device__ __forceinline__ float bf2f(unsigned short u) {
    union { unsigned u; float f; } v; v.u = ((unsigned)u) << 16; return v.f;
}

// ---------------------------------------------------------------------------
// f32 -> bf16 bulk convert (standalone; fusing into hist was a measured loss)
// ---------------------------------------------------------------------------
__global__ void __launch_bounds__(256) cvt_f32_bf16_kernel(
    const float* __restrict__ in, unsigned short* __restrict__ out, int n4)
{
    int stride = gridDim.x * 256;
    for (int i = blockIdx.x * 256 + threadIdx.x; i < n4; i += stride) {
        float4 v = *reinterpret_cast<const float4*>(in + (size_t)i * 4);
        us4 b = { f2bf(v.x), f2bf(v.y), f2bf(v.z), f2bf(v.w) };
        *reinterpret_cast<us4*>(out + (size_t)i * 4) = b;
    }
}

// ===========================================================================
// NEW bucketed CSR builder (tier A): LDS-atomic binning, ~200k global atomics
// Edge direction: bucket = ev>>6 (64 bins each);  payload packed (nv<<6)|(ev&63)
// Node direction: bucket = nv>>7 (128 bins each); payload packed (ev<<7)|(nv&127)
// ===========================================================================

// K1: per-block LDS bucket histogram; returning global atomic per non-empty
// bucket gives this block's base within the bucket (arrival order).
__global__ void __launch_bounds__(1024) part_hist_kernel(
    const int* __restrict__ node_idx, const int* __restrict__ edge_idx,
    int* __restrict__ gCntE, int* __restrict__ gCntV,
    int* __restrict__ blockBaseE, int* __restrict__ blockBaseV,
    int NBE, int NBV, int I)
{
    __shared__ int hE[MAXB];
    __shared__ int hV[MAXB];
    const int tid = threadIdx.x, blk = blockIdx.x;
    for (int k = tid; k < NBE; k += 1024) hE[k] = 0;
    for (int k = tid; k < NBV; k += 1024) hV[k] = 0;
    __syncthreads();
    const int base = blk * PART_ELEMS;
    #pragma unroll
    for (int j = 0; j < PART_ELEMS / 1024; ++j) {
        int i = base + j * 1024 + tid;
        if (i < I) {
            atomicAdd(&hE[edge_idx[i] >> 6], 1);
            atomicAdd(&hV[node_idx[i] >> 7], 1);
        }
    }
    __syncthreads();
    for (int k = tid; k < NBE; k += 1024) {
        int c = hE[k];
        blockBaseE[(size_t)blk * NBE + k] = c ? atomicAdd(&gCntE[k], c) : 0;
    }
    for (int k = tid; k < NBV; k += 1024) {
        int c = hV[k];
        blockBaseV[(size_t)blk * NBV + k] = c ? atomicAdd(&gCntV[k], c) : 0;
    }
}

// K2: exclusive scan of bucket totals (n <= 1024), appends total at out[n].
// block 0: edge direction, block 1: node direction.
__global__ void __launch_bounds__(1024) bucket_scan_kernel(
    const int* __restrict__ inE, int* __restrict__ outE, int nE,
    const int* __restrict__ inV, int* __restrict__ outV, int nV)
{
    __shared__ int lds[1024];
    const int* in  = blockIdx.x ? inV : inE;
    int*       out = blockIdx.x ? outV : outE;
    const int  n   = blockIdx.x ? nV : nE;
    const int tid = threadIdx.x;
    int v = (tid < n) ? in[tid] : 0;
    lds[tid] = v;
    __syncthreads();
    for (int o = 1; o < 1024; o <<= 1) {
        int t = lds[tid];
        int u = (tid >= o) ? lds[tid - o] : 0;
        __syncthreads();
        lds[tid] = t + u;
        __syncthreads();
    }
    if (tid < n) out[tid] = lds[tid] - v;   // exclusive
    if (tid == 0) out[n] = lds[1023];       // total
}

// K3: scatter packed pairs into bucket-partitioned order (LDS slot atomics).
__global__ void __launch_bounds__(1024) part_scatter_kernel(
    const int* __restrict__ node_idx, const int* __restrict__ edge_idx,
    const int* __restrict__ bktBaseE, const int* __restrict__ bktBaseV,
    const int* __restrict__ blockBaseE, const int* __restrict__ blockBaseV,
    int* __restrict__ pairsE, int* __restrict__ pairsV,
    int NBE, int NBV, int I)
{
    __shared__ int bE[MAXB];
    __shared__ int bV[MAXB];
    const int tid = threadIdx.x, blk = blockIdx.x;
    for (int k = tid; k < NBE; k += 1024)
        bE[k] = bktBaseE[k] + blockBaseE[(size_t)blk * NBE + k];
    for (int k = tid; k < NBV; k += 1024)
        bV[k] = bktBaseV[k] + blockBaseV[(size_t)blk * NBV + k];
    __syncthreads();
    const int base = blk * PART_ELEMS;
    #pragma unroll
    for (int j = 0; j < PART_ELEMS / 1024; ++j) {
        int i = base + j * 1024 + tid;
        if (i < I) {
            int ev = edge_idx[i], nv = node_idx[i];
            int pE = atomicAdd(&bE[ev >> 6], 1);
            pairsE[pE] = (nv << 6) | (ev & 63);
            int pV = atomicAdd(&bV[nv >> 7], 1);
            pairsV[pV] = (ev << 7) | (nv & 127);
        }
    }
}

// K4: one block per bucket: bin-level histogram -> 64/128-bin scan ->
// emits off/cnt per bin + final sorted payload arrays.
__global__ void __launch_bounds__(256) bin_csr_kernel(
    const int* __restrict__ pairsE, const int* __restrict__ pairsV,
    const int* __restrict__ bktBaseE, const int* __restrict__ bktBaseV,
    int* __restrict__ offE, int* __restrict__ cntE,
    int* __restrict__ offV, int* __restrict__ cntV,
    int* __restrict__ sorted_n, int* __restrict__ sorted_e,
    int NBE, int NBV, int E, int V)
{
    __shared__ int cnt[128], off[128], cur[128];
    const int tid = threadIdx.x;
    const int blk = blockIdx.x;
    if (blk < NBE) {
        const int k = blk, lo = bktBaseE[k], hi = bktBaseE[k + 1];
        if (tid < 64) cnt[tid] = 0;
        __syncthreads();
        for (int i = lo + tid; i < hi; i += 256)
            atomicAdd(&cnt[pairsE[i] & 63], 1);
        __syncthreads();
        if (tid < 64) off[tid] = cnt[tid];
        __syncthreads();
        for (int o = 1; o < 64; o <<= 1) {
            int t = 0;
            if (tid < 64) { t = off[tid]; if (tid >= o) t += off[tid - o]; }
            __syncthreads();
            if (tid < 64) off[tid] = t;
            __syncthreads();
        }
        if (tid < 64) {
            int excl = off[tid] - cnt[tid];
            int bin = k * 64 + tid;
            if (bin < E) { cntE[bin] = cnt[tid]; offE[bin] = lo + excl; }
            cur[tid] = 0;
            off[tid] = excl;
        }
        __syncthreads();
        for (int i = lo + tid; i < hi; i += 256) {
            int w = pairsE[i];
            int b = w & 63;
            int r = atomicAdd(&cur[b], 1);
            sorted_n[lo + off[b] + r] = w >> 6;
        }
    } else {
        const int k = blk - NBE, lo = bktBaseV[k], hi = bktBaseV[k + 1];
        if (tid < 128) cnt[tid] = 0;
        __syncthreads();
        for (int i = lo + tid; i < hi; i += 256)
            atomicAdd(&cnt[pairsV[i] & 127], 1);
        __syncthreads();
        if (tid < 128) off[tid] = cnt[tid];
        __syncthreads();
        for (int o = 1; o < 128; o <<= 1) {
            int t = 0;
            if (tid < 128) { t = off[tid]; if (tid >= o) t += off[tid - o]; }
            __syncthreads();
            if (tid < 128) off[tid] = t;
            __syncthreads();
        }
        if (tid < 128) {
            int excl = off[tid] - cnt[tid];
            int bin = k * 128 + tid;
            if (bin < V) { cntV[bin] = cnt[tid]; offV[bin] = lo + excl; }
            cur[tid] = 0;
            off[tid] = excl;
        }
        __syncthreads();
        for (int i = lo + tid; i < hi; i += 256) {
            int w = pairsV[i];
            int b = w & 127;
            int r = atomicAdd(&cur[b], 1);
            sorted_e[lo + off[b] + r] = w >> 7;
        }
    }
}

// ===========================================================================
// Old CSR builder kernels (tier B fallback) + atomic scatter (tier C)
// ===========================================================================
__global__ void __launch_bounds__(256) scatter_kernel(
    const float* __restrict__ feat, const float* __restrict__ w_num,
    const float* __restrict__ w_den, const int* __restrict__ src_idx,
    const int* __restrict__ dst_idx, float* __restrict__ acc, int n_inc)
{
    int gid = blockIdx.x * 256 + threadIdx.x;
    int inc = gid >> 5;
    if (inc >= n_inc) return;
    int c = (gid & 31) << 2;
    int s = src_idx[inc];
    int t = dst_idx[inc];
    float w = w_num[s] / w_den[t];
    float4 v = *reinterpret_cast<const float4*>(feat + (size_t)s * D + c);
    float* dst = acc + (size_t)t * D + c;
    atomicAdd(dst + 0, w * v.x);
    atomicAdd(dst + 1, w * v.y);
    atomicAdd(dst + 2, w * v.z);
    atomicAdd(dst + 3, w * v.w);
}

__global__ void __launch_bounds__(256) hist_rank_kernel(
    const int* __restrict__ node_idx, const int* __restrict__ edge_idx,
    int* __restrict__ cnt, int* __restrict__ rank_e, int* __restrict__ rank_v,
    int E, int n)
{
    int half = (n + 1) >> 1;
    int i = blockIdx.x * 256 + threadIdx.x;
    if (i >= half) return;
    int nv0 = node_idx[i], ev0 = edge_idx[i];
    int j = i + half;
    if (j < n) {
        int nv1 = node_idx[j], ev1 = edge_idx[j];
        int a = atomicAdd(&cnt[ev0], 1);
        int b = atomicAdd(&cnt[ev1], 1);
        int c = atomicAdd(&cnt[E + nv0], 1);
        int d = atomicAdd(&cnt[E + nv1], 1);
        rank_e[i] = a; rank_e[j] = b;
        rank_v[i] = c; rank_v[j] = d;
    } else {
        rank_e[i] = atomicAdd(&cnt[ev0], 1);
        rank_v[i] = atomicAdd(&cnt[E + nv0], 1);
    }
}

__global__ void __launch_bounds__(1024) scan_block_kernel(
    const int* __restrict__ in, int* __restrict__ out,
    int* __restrict__ blocksums, int n)
{
    __shared__ int lds[1024];
    const int tid = threadIdx.x;
    const int idx = blockIdx.x * SCAN_CHUNK + tid * 4;
    int4 v = make_int4(0, 0, 0, 0);
    if (idx + 3 < n) v = *reinterpret_cast<const int4*>(in + idx);
    else {
        if (idx + 0 < n) v.x = in[idx + 0];
        if (idx + 1 < n) v.y = in[idx + 1];
        if (idx + 2 < n) v.z = in[idx + 2];
        if (idx + 3 < n) v.w = in[idx + 3];
    }
    lds[tid] = v.x + v.y + v.z + v.w;
    __syncthreads();
    for (int off = 1; off < 1024; off <<= 1) {
        int t = lds[tid];
        int u = (tid >= off) ? lds[tid - off] : 0;
        __syncthreads();
        lds[tid] = t + u;
        __syncthreads();
    }
    int excl = tid ? lds[tid - 1] : 0;
    if (blocksums && tid == 1023) blocksums[blockIdx.x] = lds[1023];
    int4 o;
    o.x = excl;
    o.y = o.x + v.x;
    o.z = o.y + v.y;
    o.w = o.z + v.z;
    if (idx + 3 < n) *reinterpret_cast<int4*>(out + idx) = o;
    else {
        if (idx + 0 < n) out[idx + 0] = o.x;
        if (idx + 1 < n) out[idx + 1] = o.y;
        if (idx + 2 < n) out[idx + 2] = o.z;
        if (idx + 3 < n) out[idx + 3] = o.w;
    }
}

__global__ void __launch_bounds__(256) place_kernel(
    const int* __restrict__ node_idx, const int* __restrict__ edge_idx,
    const int* __restrict__ rank_e, const int* __restrict__ rank_v,
    const int* __restrict__ off, const int* __restrict__ bsum,
    int* __restrict__ sorted_n, int* __restrict__ sorted_e,
    int E, int I)
{
    int i = blockIdx.x * 256 + threadIdx.x;
    if (i >= I) return;
    int nv = node_idx[i], ev = edge_idx[i];
    sorted_n[off[ev] + bsum[ev >> 12] + rank_e[i]] = nv;
    int b2 = E + nv;
    sorted_e[off[b2] + bsum[b2 >> 12] - I + rank_v[i]] = ev;
}

// ---------------------------------------------------------------------------
// gather-sum: 32 lanes per destination row (4 cols/lane), 8 rows per block.
// bsum==nullptr -> off[] is absolute. BR: fused +bias, relu epilogue.
// ---------------------------------------------------------------------------
template <int IN_BF>
__device__ __forceinline__ float4 ldrow4(const void* feat, int s, int c) {
    if constexpr (IN_BF) {
        us4 v = *reinterpret_cast<const us4*>(
            (const unsigned short*)feat + (size_t)s * D + c);
        return make_float4(bf2f(v[0]), bf2f(v[1]), bf2f(v[2]), bf2f(v[3]));
    } else {
        return *reinterpret_cast<const float4*>((const float*)feat + (size_t)s * D + c);
    }
}

template <int IN_BF, int OUT_BF, int BR>
__global__ void __launch_bounds__(256) gather_seg_kernel(
    const void* __restrict__ feat, const float* __restrict__ w_num,
    const float* __restrict__ w_den, const int* __restrict__ sorted_src,
    const int* __restrict__ off, const int* __restrict__ bsum,
    const int* __restrict__ cnt, int binBase, int sortBase,
    const float* __restrict__ bias,
    void* __restrict__ out, int n_dst)
{
    int row = blockIdx.x * 8 + (threadIdx.x >> 5);
    if (row >= n_dst) return;
    int c = (threadIdx.x & 31) << 2;
    int bin = binBase + row;
    int start = off[bin] + sortBase;
    if (bsum) start += bsum[bin >> 12];
    const int* sp = sorted_src + start;
    int n = cnt[bin];
    float inv = 1.0f / w_den[row];
    float a0 = 0.f, a1 = 0.f, a2 = 0.f, a3 = 0.f;
    int i = 0;
    for (; i + 2 <= n; i += 2) {
        int s0 = sp[i], s1 = sp[i + 1];
        float w0 = w_num[s0], w1 = w_num[s1];
        float4 f0 = ldrow4<IN_BF>(feat, s0, c);
        float4 f1 = ldrow4<IN_BF>(feat, s1, c);
        a0 = fmaf(w0, f0.x, a0); a1 = fmaf(w0, f0.y, a1);
        a2 = fmaf(w0, f0.z, a2); a3 = fmaf(w0, f0.w, a3);
        a0 = fmaf(w1, f1.x, a0); a1 = fmaf(w1, f1.y, a1);
        a2 = fmaf(w1, f1.z, a2); a3 = fmaf(w1, f1.w, a3);
    }
    if (i < n) {
        int s0 = sp[i];
        float w0 = w_num[s0];
        float4 f0 = ldrow4<IN_BF>(feat, s0, c);
        a0 = fmaf(w0, f0.x, a0); a1 = fmaf(w0, f0.y, a1);
        a2 = fmaf(w0, f0.z, a2); a3 = fmaf(w0, f0.w, a3);
    }
    a0 *= inv; a1 *= inv; a2 *= inv; a3 *= inv;
    if constexpr (BR) {
        float4 bv = *reinterpret_cast<const float4*>(bias + c);
        a0 = fmaxf(a0 + bv.x, 0.f); a1 = fmaxf(a1 + bv.y, 0.f);
        a2 = fmaxf(a2 + bv.z, 0.f); a3 = fmaxf(a3 + bv.w, 0.f);
    }
    if constexpr (OUT_BF) {
        us4 o = { f2bf(a0), f2bf(a1), f2bf(a2), f2bf(a3) };
        *reinterpret_cast<us4*>((unsigned short*)out + (size_t)row * D + c) = o;
    } else {
        float4 o = make_float4(a0, a1, a2, a3);
        *reinterpret_cast<float4*>((float*)out + (size_t)row * D + c) = o;
    }
}

// ---------------------------------------------------------------------------
// LDS staging helpers for MFMA GEMMs.
// ---------------------------------------------------------------------------
__device__ __forceinline__ void stage_A64(
    unsigned short* A_lds, const float* __restrict__ in, int r0, int nrows, int tid)
{
    #pragma unroll
    for (int it = 0; it < 8; ++it) {
        int e   = tid + it * 256;
        int row = e >> 5;
        int c4  = (e & 31) << 2;
        int grow = r0 + row;
        float4 v = make_float4(0.f, 0.f, 0.f, 0.f);
        if (grow < nrows)
            v = *reinterpret_cast<const float4*>(in + (size_t)grow * D + c4);
        us4 b = { f2bf(v.x), f2bf(v.y), f2bf(v.z), f2bf(v.w) };
        *reinterpret_cast<us4*>(A_lds + row * LDSP + c4) = b;
    }
}

__device__ __forceinline__ void stage_A64_bf(
    unsigned short* A_lds, const unsigned short* __restrict__ in,
    int r0, int nrows, int tid)
{
    #pragma unroll
    for (int it = 0; it < 4; ++it) {
        int e   = tid + it * 256;
        int row = e >> 4;
        int c8  = (e & 15) << 3;
        int grow = r0 + row;
        bf16x8 v;
        #pragma unroll
        for (int j = 0; j < 8; ++j) v[j] = 0;
        if (grow < nrows)
            v = *reinterpret_cast<const bf16x8*>(in + (size_t)grow * D + c8);
        *reinterpret_cast<bf16x8*>(A_lds + row * LDSP + c8) = v;
    }
}

__device__ __forceinline__ void stage_W(
    unsigned short* W_lds, const float* __restrict__ W, int tid)
{
    #pragma unroll
    for (int it = 0; it < 16; ++it) {
        int e   = tid + it * 256;
        int row = e >> 5;
        int c4  = (e & 31) << 2;
        float4 v = *reinterpret_cast<const float4*>(W + (size_t)row * D + c4);
        us4 b = { f2bf(v.x), f2bf(v.y), f2bf(v.z), f2bf(v.w) };
        *reinterpret_cast<us4*>(W_lds + row * LDSP + c4) = b;
    }
}

__device__ __forceinline__ void mfma_16x128(
    const unsigned short* A_lds, const unsigned short* W_lds,
    int wv, int lane, f32x4 acc[8])
{
    const int lr = lane & 15;
    const int lk = (lane >> 4) << 3;
    const unsigned short* arow = A_lds + (wv * 16 + lr) * LDSP;
    #pragma unroll
    for (int kt = 0; kt < 4; ++kt) {
        bf16x8 af = *reinterpret_cast<const bf16x8*>(arow + kt * 32 + lk);
        #pragma unroll
        for (int ct = 0; ct < 8; ++ct) {
            bf16x8 bfr = *reinterpret_cast<const bf16x8*>(
                W_lds + (ct * 16 + lr) * LDSP + kt * 32 + lk);
            acc[ct] = __builtin_amdgcn_mfma_f32_16x16x32_bf16(af, bfr, acc[ct], 0, 0, 0);
        }
    }
}

template <int MODE>
__global__ void __launch_bounds__(256) mfma_gemm_kernel(
    const float* __restrict__ in, const float* __restrict__ W,
    const float* __restrict__ bias, float* __restrict__ out, int nrows)
{
    __shared__ unsigned short A_lds[64 * LDSP];
    __shared__ unsigned short W_lds[D * LDSP];

    const int tid  = threadIdx.x;
    const int r0   = blockIdx.x * 64;
    const int wv   = tid >> 6;
    const int lane = tid & 63;

    stage_A64(A_lds, in, r0, nrows, tid);
    stage_W(W_lds, W, tid);
    __syncthreads();

    f32x4 acc[8];
    #pragma unroll
    for (int ct = 0; ct < 8; ++ct) acc[ct] = (f32x4){0.f, 0.f, 0.f, 0.f};
    mfma_16x128(A_lds, W_lds, wv, lane, acc);

    const int lr = lane & 15;
    const int rb = r0 + wv * 16 + ((lane >> 4) << 2);
    #pragma unroll
    for (int ct = 0; ct < 8; ++ct) {
        int col = ct * 16 + lr;
        float bv = bias[col];
        #pragma unroll
        for (int i = 0; i < 4; ++i) {
            int row = rb + i;
            if (row >= nrows) continue;
            float x = acc[ct][i] + bv;
            if (MODE == 2) x = fmaxf(x, 0.f);
            out[(size_t)row * D + col] = x;
        }
    }
}

template <int RBF>
__global__ void __launch_bounds__(256) mfma_dualgemm_kernel(
    const float* __restrict__ inL, const float* __restrict__ WL,
    const float* __restrict__ bL,
    const void*  __restrict__ inR, const float* __restrict__ WR,
    const float* __restrict__ bR,
    float* __restrict__ out, int nrows)
{
    __shared__ unsigned short A_lds[64 * LDSP];
    __shared__ unsigned short W_lds[D * LDSP];

    const int tid  = threadIdx.x;
    const int r0   = blockIdx.x * 64;
    const int wv   = tid >> 6;
    const int lane = tid & 63;

    f32x4 acc0[8], acc1[8];
    #pragma unroll
    for (int ct = 0; ct < 8; ++ct) {
        acc0[ct] = (f32x4){0.f, 0.f, 0.f, 0.f};
        acc1[ct] = (f32x4){0.f, 0.f, 0.f, 0.f};
    }

    stage_A64(A_lds, inL, r0, nrows, tid);
    stage_W(W_lds, WL, tid);
    __syncthreads();
    mfma_16x128(A_lds, W_lds, wv, lane, acc0);
    __syncthreads();

    if constexpr (RBF)
        stage_A64_bf(A_lds, (const unsigned short*)inR, r0, nrows, tid);
    else
        stage_A64(A_lds, (const float*)inR, r0, nrows, tid);
    stage_W(W_lds, WR, tid);
    __syncthreads();
    mfma_16x128(A_lds, W_lds, wv, lane, acc1);

    const int lr = lane & 15;
    const int rb = r0 + wv * 16 + ((lane >> 4) << 2);
    #pragma unroll
    for (int ct = 0; ct < 8; ++ct) {
        int col = ct * 16 + lr;
        float bvL = bL[col];
        float bvR = bR[col];
        #pragma unroll
        for (int i = 0; i < 4; ++i) {
            int row = rb + i;
            if (row >= nrows) continue;
            float x = (acc0[ct][i] + bvL) + fmaxf(acc1[ct][i] + bvR, 0.f);
            out[(size_t)row * D + col] = x;
        }
    }
}

// ---------------------------------------------------------------------------
// TRIPLE GEMM (tier A):
//   eout = (inL @ WL^T + bL) + relu(inR_bf @ WR^T + bR)   -> outE (f32)
//   Z    = eout @ WZ^T                                     -> outZ (bf16)
// ---------------------------------------------------------------------------
__global__ void __launch_bounds__(256) mfma_trigemm_kernel(
    const float* __restrict__ inL, const float* __restrict__ WL,
    const float* __restrict__ bL,
    const unsigned short* __restrict__ inR, const float* __restrict__ WR,
    const float* __restrict__ bR,
    const float* __restrict__ WZ,
    float* __restrict__ outE, unsigned short* __restrict__ outZ, int nrows)
{
    __shared__ unsigned short A_lds[64 * LDSP];
    __shared__ unsigned short W_lds[D * LDSP];

    const int tid  = threadIdx.x;
    const int r0   = blockIdx.x * 64;
    const int wv   = tid >> 6;
    const int lane = tid & 63;
    const int lr   = lane & 15;
    const int lg   = lane >> 4;
    const int rb   = r0 + wv * 16 + (lg << 2);

    f32x4 acc0[8], acc1[8];
    #pragma unroll
    for (int ct = 0; ct < 8; ++ct) {
        acc0[ct] = (f32x4){0.f, 0.f, 0.f, 0.f};
        acc1[ct] = (f32x4){0.f, 0.f, 0.f, 0.f};
    }

    stage_A64(A_lds, inL, r0, nrows, tid);
    stage_W(W_lds, WL, tid);
    __syncthreads();
    mfma_16x128(A_lds, W_lds, wv, lane, acc0);
    __syncthreads();

    stage_A64_bf(A_lds, inR, r0, nrows, tid);
    stage_W(W_lds, WR, tid);
    __syncthreads();
    mfma_16x128(A_lds, W_lds, wv, lane, acc1);

    float ev[8][4];
    #pragma unroll
    for (int ct = 0; ct < 8; ++ct) {
        int col = ct * 16 + lr;
        float bvL = bL[col];
        float bvR = bR[col];
        #pragma unroll
        for (int i = 0; i < 4; ++i) {
            float x = (acc0[ct][i] + bvL) + fmaxf(acc1[ct][i] + bvR, 0.f);
            ev[ct][i] = x;
            int row = rb + i;
            if (row < nrows) outE[(size_t)row * D + col] = x;
        }
    }

    __syncthreads();

    #pragma unroll
    for (int ct = 0; ct < 8; ++ct) {
        int col = ct * 16 + lr;
        #pragma unroll
        for (int i = 0; i < 4; ++i) {
            A_lds[(wv * 16 + (lg << 2) + i) * LDSP + col] = f2bf(ev[ct][i]);
        }
    }
    stage_W(W_lds, WZ, tid);
    __syncthreads();

    f32x4 accZ[8];
    #pragma unroll
    for (int ct = 0; ct < 8; ++ct) accZ[ct] = (f32x4){0.f, 0.f, 0.f, 0.f};
    mfma_16x128(A_lds, W_lds, wv, lane, accZ);

    #pragma unroll
    for (int ct = 0; ct < 8; ++ct) {
        int col = ct * 16 + lr;
        #pragma unroll
        for (int i = 0; i < 4; ++i) {
            int row = rb + i;
            if (row < nrows) outZ[(size_t)row * D + col] = f2bf(accZ[ct][i]);
        }
    }
}

// ---------------------------------------------------------------------------
extern "C" void kernel_launch(void* const* d_in, const int* in_sizes, int n_in,
                              void* d_out, int out_size, void* d_ws, size_t ws_size,
                              hipStream_t stream)
{
    const float* vfeat = (const float*)d_in[0];
    const float* efeat = (const float*)d_in[1];
    const float* vrw   = (const float*)d_in[2];
    const float* vrs   = (const float*)d_in[3];
    const float* erw   = (const float*)d_in[4];
    const float* ers   = (const float*)d_in[5];
    const float* W_ve  = (const float*)d_in[6];
    const float* b_ve  = (const float*)d_in[7];
    const float* W_ev  = (const float*)d_in[8];
    const float* b_ev  = (const float*)d_in[9];
    const float* W_ef  = (const float*)d_in[10];
    const float* b_ef  = (const float*)d_in[11];
    const int* node_idx = (const int*)d_in[12];
    const int* edge_idx = (const int*)d_in[13];

    const int V = in_sizes[0] / D;   // 100000
    const int E = in_sizes[1] / D;   // 40000
    const int I = in_sizes[12];      // 600000
    const int EV = E + V;

    float* vfeat_out = (float*)d_out;                  // [V, D]
    float* efeat_out = (float*)d_out + (size_t)V * D;  // [E, D]

    const int NBE = (E + 63) >> 6;    // 625 edge buckets (64 bins each)
    const int NBV = (V + 127) >> 7;   // 782 node buckets (128 bins each)
    const int HB  = (I + PART_ELEMS - 1) / PART_ELEMS;  // 147

    // ---- new tier-A workspace layout ----
    int* gCntE      = (int*)d_ws;                 // [NBE]   (zeroed)
    int* gCntV      = gCntE + NBE;                // [NBV]   (zeroed, adjacent)
    int* bktBaseE   = gCntV + NBV;                // [NBE+1]
    int* bktBaseV   = bktBaseE + NBE + 1;         // [NBV+1]
    int* blockBaseE = bktBaseV + NBV + 1;         // [HB*NBE]
    int* blockBaseV = blockBaseE + (size_t)HB * NBE; // [HB*NBV]
    int* offE       = blockBaseV + (size_t)HB * NBV; // [E]
    int* cntE       = offE + E;                   // [E]
    int* offV       = cntE + E;                   // [V]
    int* cntV       = offV + V;                   // [V]
    int* sorted_n   = cntV + V;                   // [I]
    int* sorted_e   = sorted_n + I;               // [I]
    size_t fixed_ints = (size_t)(sorted_e + I - (int*)d_ws);
    fixed_ints = (fixed_ints + 3) & ~(size_t)3;   // 16B-align the union region
    // union region: pairsE/pairsV (2I ints, dead after bin_csr)  vs  z_bf
    int* pairsE = (int*)d_ws + fixed_ints;
    int* pairsV = pairsE + I;
    unsigned short* z_bf = (unsigned short*)pairsE;   // [E*D] born at trigemm
    size_t union_bytes = (size_t)2 * I * 4;
    if ((size_t)E * D * 2 > union_bytes) union_bytes = (size_t)E * D * 2;
    size_t ws_needA = fixed_ints * 4 + union_bytes;

    // old tier-B layout (f32 gathers, bsum-folded)
    size_t ws_needB = ((size_t)2 * EV + 64 + (size_t)4 * I) * sizeof(int);

    if (ws_size >= ws_needA && NBE <= 1024 && NBV <= 1024) {
        // ======== tier A: bucketed CSR + bf16 gathers + fused triple GEMM ====
        unsigned short* vfeat_bf = (unsigned short*)d_out;       // [V*D]
        unsigned short* acc_e_bf = vfeat_bf + (size_t)V * D;     // [E*D]
        // 25.6 + 10.2 MB <= 51.2 MB f32 region; dead before gather2 writes.

        hipMemsetAsync(gCntE, 0, (size_t)(NBE + NBV) * sizeof(int), stream);
        part_hist_kernel<<<HB, 1024, 0, stream>>>(
            node_idx, edge_idx, gCntE, gCntV, blockBaseE, blockBaseV, NBE, NBV, I);
        cvt_f32_bf16_kernel<<<2048, 256, 0, stream>>>(vfeat, vfeat_bf, V * D / 4);
        bucket_scan_kernel<<<2, 1024, 0, stream>>>(
            gCntE, bktBaseE, NBE, gCntV, bktBaseV, NBV);
        part_scatter_kernel<<<HB, 1024, 0, stream>>>(
            node_idx, edge_idx, bktBaseE, bktBaseV, blockBaseE, blockBaseV,
            pairsE, pairsV, NBE, NBV, I);
        bin_csr_kernel<<<NBE + NBV, 256, 0, stream>>>(
            pairsE, pairsV, bktBaseE, bktBaseV,
            offE, cntE, offV, cntV, sorted_n, sorted_e, NBE, NBV, E, V);

        // g1: nodes -> hyperedges (bf16 table, bf16 out)
        gather_seg_kernel<1, 1, 0><<<(E + 7) / 8, 256, 0, stream>>>(
            vfeat_bf, vrw, ers, sorted_n, offE, nullptr, cntE, 0, 0,
            nullptr, acc_e_bf, E);

        // eout = (efeat@W_ef^T+b_ef) + relu(acc_e@W_ve^T+b_ve);  Z = eout@W_ev^T
        mfma_trigemm_kernel<<<(E + 63) / 64, 256, 0, stream>>>(
            efeat, W_ef, b_ef, acc_e_bf, W_ve, b_ve, W_ev, efeat_out, z_bf, E);

        // g2: vfeat_out = relu( (sum w * Z[e]) / vrs + b_ev )
        gather_seg_kernel<1, 0, 1><<<(V + 7) / 8, 256, 0, stream>>>(
            z_bf, erw, vrs, sorted_e, offV, nullptr, cntV, 0, 0,
            b_ev, vfeat_out, V);
    } else if (ws_size >= ws_needB) {
        // ======== tier B: old atomic hist + place, f32 gathers ========
        int* cnt_cat  = (int*)d_ws;
        int* off_cat  = cnt_cat + EV;
        int* bsum     = off_cat + EV;
        int* rank_e   = bsum + 64;
        int* rank_v   = rank_e + I;
        int* sorted_nb = rank_v + I;
        int* sorted_eb = sorted_nb + I;
        const int inc_blocks  = (I + 255) / 256;
        const int half_blocks = (((I + 1) >> 1) + 255) / 256;
        const int nb = (EV + SCAN_CHUNK - 1) / SCAN_CHUNK;
        float* acc_e = vfeat_out;

        hipMemsetAsync(cnt_cat, 0, (size_t)EV * sizeof(int), stream);
        hist_rank_kernel<<<half_blocks, 256, 0, stream>>>(
            node_idx, edge_idx, cnt_cat, rank_e, rank_v, E, I);
        scan_block_kernel<<<nb, 1024, 0, stream>>>(cnt_cat, off_cat, bsum, EV);
        scan_block_kernel<<<1, 1024, 0, stream>>>(bsum, bsum, nullptr, nb);
        place_kernel<<<inc_blocks, 256, 0, stream>>>(
            node_idx, edge_idx, rank_e, rank_v, off_cat, bsum, sorted_nb, sorted_eb, E, I);
        gather_seg_kernel<0, 0, 0><<<(E + 7) / 8, 256, 0, stream>>>(
            vfeat, vrw, ers, sorted_nb, off_cat, bsum, cnt_cat, 0, 0,
            nullptr, acc_e, E);
        mfma_dualgemm_kernel<0><<<(E + 63) / 64, 256, 0, stream>>>(
            efeat, W_ef, b_ef, acc_e, W_ve, b_ve, efeat_out, E);
        gather_seg_kernel<0, 0, 0><<<(V + 7) / 8, 256, 0, stream>>>(
            efeat_out, erw, vrs, sorted_eb, off_cat, bsum, cnt_cat, E, -I,
            nullptr, vfeat_out, V);
        mfma_gemm_kernel<2><<<(V + 63) / 64, 256, 0, stream>>>(
            vfeat_out, W_ev, b_ev, vfeat_out, V);
    } else {
        // ======== tier C: atomic fallback ========
        float* acc_e = vfeat_out;
        const int sb = (I * 32 + 255) / 256;
        hipMemsetAsync(acc_e, 0, (size_t)E * D * sizeof(float), stream);
        scatter_kernel<<<sb, 256, 0, stream>>>(vfeat, vrw, ers, node_idx, edge_idx, acc_e, I);
        mfma_dualgemm_kernel<0><<<(E + 63) / 64, 256, 0, stream>>>(
            efeat, W_ef, b_ef, acc_e, W_ve, b_ve, efeat_out, E);
        hipMemsetAsync(vfeat_out, 0, (size_t)V * D * sizeof(float), stream);
        scatter_kernel<<<sb, 256, 0, stream>>>(efeat_out, erw, vrs, edge_idx, node_idx, vfeat_out, I);
        mfma_gemm_kernel<2><<<(V + 63) / 64, 256, 0, stream>>>(vfeat_out, W_ev, b_ev, vfeat_out, V);
    }
}